// Round 5
// baseline (403.720 us; speedup 1.0000x reference)
//
#include <hip/hip_runtime.h>

#define NNODES 50000
#define NEDGES 800000
#define SCAN_BLOCKS 196   // ceil(50000/256)
#define FILL_CHUNK 14336  // mult of 1024; 56 chunks cover 802816 >= NEDGES
#define FILL_NCHUNK 56

using bf16x8  = __attribute__((ext_vector_type(8))) __bf16;
using floatx4 = __attribute__((ext_vector_type(4))) float;
using int4v   = __attribute__((ext_vector_type(4))) int;
using float4v = __attribute__((ext_vector_type(4))) float;
using uint2v  = __attribute__((ext_vector_type(2))) unsigned int;

__device__ __forceinline__ float bf2f(unsigned short u) {
  unsigned int v = ((unsigned int)u) << 16;
  return __builtin_bit_cast(float, v);
}
__device__ __forceinline__ unsigned short f2bf(float f) {
  unsigned int u = __builtin_bit_cast(unsigned int, f);
  u += 0x7fffu + ((u >> 16) & 1u);  // RNE
  return (unsigned short)(u >> 16);
}

__global__ void zero_int_kernel(int* __restrict__ p, int n) {
  int i = blockIdx.x * blockDim.x + threadIdx.x;
  if (i < n) p[i] = 0;
}

// grid-stride, int4 nontemporal loads (edge list read exactly once here)
__global__ __launch_bounds__(256) void degree_kernel(const int* __restrict__ dst,
                                                     int* __restrict__ deg) {
  int i = blockIdx.x * blockDim.x + threadIdx.x;
  int stride = gridDim.x * blockDim.x;
  const int n4 = NEDGES / 4;
  for (; i < n4; i += stride) {
    int4v d = __builtin_nontemporal_load((const int4v*)dst + i);
    atomicAdd(&deg[d.x], 1);
    atomicAdd(&deg[d.y], 1);
    atomicAdd(&deg[d.z], 1);
    atomicAdd(&deg[d.w], 1);
  }
}

// ---- multi-block exclusive scan of deg -> row_start/cursor/inv_deg ----
__global__ __launch_bounds__(256) void block_sum_kernel(const int* __restrict__ deg,
                                                        int* __restrict__ blocksum) {
  __shared__ int s[256];
  int i = blockIdx.x * 256 + threadIdx.x;
  s[threadIdx.x] = (i < NNODES) ? deg[i] : 0;
  __syncthreads();
  for (int off = 128; off > 0; off >>= 1) {
    if (threadIdx.x < off) s[threadIdx.x] += s[threadIdx.x + off];
    __syncthreads();
  }
  if (threadIdx.x == 0) blocksum[blockIdx.x] = s[0];
}

__global__ __launch_bounds__(256) void scan_blocksum_kernel(const int* __restrict__ blocksum,
                                                            int* __restrict__ blockoff) {
  __shared__ int s[256];
  int t = threadIdx.x;
  s[t] = (t < SCAN_BLOCKS) ? blocksum[t] : 0;
  __syncthreads();
  for (int off = 1; off < 256; off <<= 1) {
    int v = s[t];
    int u = (t >= off) ? s[t - off] : 0;
    __syncthreads();
    s[t] = v + u;
    __syncthreads();
  }
  if (t < SCAN_BLOCKS) blockoff[t] = (t == 0) ? 0 : s[t - 1];
}

__global__ __launch_bounds__(256) void apply_scan_kernel(
    const int* __restrict__ deg, const int* __restrict__ blockoff,
    int* __restrict__ row_start, int* __restrict__ cursor, float* __restrict__ inv_deg) {
  __shared__ int s[256];
  int t = threadIdx.x;
  int i = blockIdx.x * 256 + t;
  int d = (i < NNODES) ? deg[i] : 0;
  s[t] = d;
  __syncthreads();
  for (int off = 1; off < 256; off <<= 1) {
    int v = s[t];
    int u = (t >= off) ? s[t - off] : 0;
    __syncthreads();
    s[t] = v + u;
    __syncthreads();
  }
  if (i < NNODES) {
    int excl = blockoff[blockIdx.x] + s[t] - d;  // inclusive - self
    row_start[i] = excl;
    cursor[i] = excl;
    inv_deg[i] = 1.0f / (float)((d > 0) ? d : 1);
  }
  if (i == 0) row_start[NNODES] = NEDGES;
}

// XCD-partitioned CSR fill (blockIdx%8 ~ XCD). Nontemporal edge-list loads so the
// 51MB read stream doesn't evict partially-filled dirty csr lines from L2.
__global__ __launch_bounds__(256) void fill_part_kernel(const int* __restrict__ src,
                                                        const int* __restrict__ dst,
                                                        int* __restrict__ cursor,
                                                        int* __restrict__ csr) {
  int p = blockIdx.x & 7;
  if (p == 7) return;  // dst < 50000 => partition 7 empty
  int chunk = blockIdx.x >> 3;
  int e0 = chunk * FILL_CHUNK;
  int e1 = min(e0 + FILL_CHUNK, NEDGES);
  for (int base = e0 + (int)threadIdx.x * 4; base < e1; base += 256 * 4) {
    int4v d4 = __builtin_nontemporal_load((const int4v*)(dst + base));
    int4v s4 = __builtin_nontemporal_load((const int4v*)(src + base));
    if ((d4.x >> 13) == p) { int pos = atomicAdd(&cursor[d4.x], 1); csr[pos] = s4.x; }
    if ((d4.y >> 13) == p) { int pos = atomicAdd(&cursor[d4.y], 1); csr[pos] = s4.y; }
    if ((d4.z >> 13) == p) { int pos = atomicAdd(&cursor[d4.z], 1); csr[pos] = s4.z; }
    if ((d4.w >> 13) == p) { int pos = atomicAdd(&cursor[d4.w], 1); csr[pos] = s4.w; }
  }
}

// fp32 -> bf16, vectorized: nontemporal float4 in (read-once), ushort4 out (cached)
__global__ void conv_x_kernel(const float* __restrict__ in, ushort4* __restrict__ out,
                              int n4) {
  int i = blockIdx.x * blockDim.x + threadIdx.x;
  int stride = gridDim.x * blockDim.x;
  for (; i < n4; i += stride) {
    float4v v = __builtin_nontemporal_load((const float4v*)in + i);
    ushort4 o;
    o.x = f2bf(v.x);
    o.y = f2bf(v.y);
    o.z = f2bf(v.z);
    o.w = f2bf(v.w);
    out[i] = o;
  }
}

struct WPtrs {
  const float* src[6];
  unsigned short* dst[6];
  int n[6];
};

__global__ void conv_weights_kernel(WPtrs p) {
  int i = blockIdx.x * blockDim.x + threadIdx.x;
#pragma unroll
  for (int s = 0; s < 6; ++s) {
    if (i < p.n[s]) {
      p.dst[s][i] = f2bf(p.src[s][i]);
      return;
    }
    i -= p.n[s];
  }
}

// one wave per node; half-wave per edge: lanes 0-31 edge e, lanes 32-63 edge e+1.
// Each lane loads uint2 = 4 channels; unroll 4 => 8 neighbor rows outstanding.
// csr reads nontemporal (sequential, no reuse within dispatch).
__global__ __launch_bounds__(256) void agg_kernel(
    const unsigned short* __restrict__ hin, unsigned short* __restrict__ aggout,
    const int* __restrict__ row_start, const int* __restrict__ csr,
    const float* __restrict__ inv_deg) {
  int gw = (blockIdx.x * blockDim.x + threadIdx.x) >> 6;  // node id
  int lane = threadIdx.x & 63;
  int half = lane >> 5;
  int c32 = lane & 31;     // channel group: channels [c32*4, c32*4+4)
  int off = c32 * 4;       // ushort offset within row
  int s0 = row_start[gw], s1 = row_start[gw + 1];
  float a0 = 0.f, a1 = 0.f, a2 = 0.f, a3 = 0.f;
  int e = s0 + half;
#define NTL(idx) __builtin_nontemporal_load(csr + (idx))
#define ACC(v)                                   \
  a0 += bf2f((unsigned short)((v).x & 0xffffu)); \
  a1 += bf2f((unsigned short)((v).x >> 16));     \
  a2 += bf2f((unsigned short)((v).y & 0xffffu)); \
  a3 += bf2f((unsigned short)((v).y >> 16));
  for (; e + 6 < s1; e += 8) {
    int i0 = NTL(e), i1 = NTL(e + 2), i2 = NTL(e + 4), i3 = NTL(e + 6);
    uint2 v0 = *(const uint2*)(hin + (size_t)i0 * 128 + off);
    uint2 v1 = *(const uint2*)(hin + (size_t)i1 * 128 + off);
    uint2 v2 = *(const uint2*)(hin + (size_t)i2 * 128 + off);
    uint2 v3 = *(const uint2*)(hin + (size_t)i3 * 128 + off);
    ACC(v0) ACC(v1) ACC(v2) ACC(v3)
  }
  for (; e < s1; e += 2) {
    int i0 = NTL(e);
    uint2 v = *(const uint2*)(hin + (size_t)i0 * 128 + off);
    ACC(v)
  }
#undef ACC
#undef NTL
  // combine the two half-wave partials (same channels, different edge subsets)
  a0 += __shfl_xor(a0, 32);
  a1 += __shfl_xor(a1, 32);
  a2 += __shfl_xor(a2, 32);
  a3 += __shfl_xor(a3, 32);
  if (half == 0) {
    float idg = inv_deg[gw];
    ushort4 o;
    o.x = f2bf(a0 * idg);
    o.y = f2bf(a1 * idg);
    o.z = f2bf(a2 * idg);
    o.w = f2bf(a3 * idg);
    *(ushort4*)(aggout + (size_t)gw * 128 + off) = o;
  }
}

__device__ __forceinline__ bf16x8 load_frag(const unsigned short* p) {
  uint4 v = *(const uint4*)p;
  return __builtin_bit_cast(bf16x8, v);
}

// Fused: out[n][j] = sum_k agg[n][k]*Wl[j][k] + sum_k h[n][k]*Wr[j][k] + bl[j]
// then (optionally) ReLU + LayerNorm. One wave = 16 rows x OUTC cols, block = 4 waves.
template <int NT, bool LNRELU, bool OUTF32>
__global__ __launch_bounds__(256) void fused_layer_kernel(
    const unsigned short* __restrict__ agg, const unsigned short* __restrict__ hin,
    const unsigned short* __restrict__ Wl, const float* __restrict__ bl,
    const unsigned short* __restrict__ Wr, const float* __restrict__ g,
    const float* __restrict__ beta, void* __restrict__ hout) {
  constexpr int OUTC = NT * 16;
  int wave = threadIdx.x >> 6;
  int lane = threadIdx.x & 63;
  int quad = lane >> 4;
  int m = lane & 15;
  int row0 = blockIdx.x * 64 + wave * 16;
  int arow = min(row0 + m, NNODES - 1);  // clamp: tail rows read row 49999, stores guarded
  const unsigned short* ap = agg + (size_t)arow * 128 + quad * 8;
  const unsigned short* hp = hin + (size_t)arow * 128 + quad * 8;
  bf16x8 aA[4], aH[4];
#pragma unroll
  for (int kt = 0; kt < 4; ++kt) {
    aA[kt] = load_frag(ap + kt * 32);
    aH[kt] = load_frag(hp + kt * 32);
  }
  floatx4 acc[NT];
#pragma unroll
  for (int t = 0; t < NT; ++t) {
    int n = t * 16 + m;
    const unsigned short* wlp = Wl + n * 128 + quad * 8;
    const unsigned short* wrp = Wr + n * 128 + quad * 8;
    floatx4 c = {0.f, 0.f, 0.f, 0.f};
#pragma unroll
    for (int kt = 0; kt < 4; ++kt)
      c = __builtin_amdgcn_mfma_f32_16x16x32_bf16(aA[kt], load_frag(wlp + kt * 32), c, 0, 0, 0);
#pragma unroll
    for (int kt = 0; kt < 4; ++kt)
      c = __builtin_amdgcn_mfma_f32_16x16x32_bf16(aH[kt], load_frag(wrp + kt * 32), c, 0, 0, 0);
    acc[t] = c;
  }
  float bias[NT];
#pragma unroll
  for (int t = 0; t < NT; ++t) bias[t] = bl[t * 16 + m];

  if constexpr (LNRELU) {
    // C layout: value at (row=quad*4+r, col=t*16+m). Row stats reduce over the
    // 16 lanes sharing `quad` (contiguous lane group -> shfl_xor width 16).
    float v[NT][4];
    float s1[4] = {0.f, 0.f, 0.f, 0.f};
    float s2[4] = {0.f, 0.f, 0.f, 0.f};
#pragma unroll
    for (int t = 0; t < NT; ++t)
#pragma unroll
      for (int r = 0; r < 4; ++r) {
        float x = acc[t][r] + bias[t];
        x = x > 0.f ? x : 0.f;  // ReLU before LN
        v[t][r] = x;
        s1[r] += x;
        s2[r] += x * x;
      }
#pragma unroll
    for (int r = 0; r < 4; ++r) {
#pragma unroll
      for (int msk = 1; msk < 16; msk <<= 1) {
        s1[r] += __shfl_xor(s1[r], msk, 16);
        s2[r] += __shfl_xor(s2[r], msk, 16);
      }
    }
    float gam[NT], bet[NT];
#pragma unroll
    for (int t = 0; t < NT; ++t) {
      gam[t] = g[t * 16 + m];
      bet[t] = beta[t * 16 + m];
    }
#pragma unroll
    for (int r = 0; r < 4; ++r) {
      int grow = row0 + quad * 4 + r;
      if (grow < NNODES) {
        float mu = s1[r] * (1.0f / OUTC);
        float var = s2[r] * (1.0f / OUTC) - mu * mu;
        float rs = rsqrtf(var + 1e-5f);
#pragma unroll
        for (int t = 0; t < NT; ++t) {
          float y = (v[t][r] - mu) * rs * gam[t] + bet[t];
          ((unsigned short*)hout)[(size_t)grow * OUTC + t * 16 + m] = f2bf(y);
        }
      }
    }
  } else {
#pragma unroll
    for (int r = 0; r < 4; ++r) {
      int grow = row0 + quad * 4 + r;
      if (grow < NNODES) {
#pragma unroll
        for (int t = 0; t < NT; ++t) {
          float y = acc[t][r] + bias[t];
          if constexpr (OUTF32)
            ((float*)hout)[(size_t)grow * OUTC + t * 16 + m] = y;
          else
            ((unsigned short*)hout)[(size_t)grow * OUTC + t * 16 + m] = f2bf(y);
        }
      }
    }
  }
}

extern "C" void kernel_launch(void* const* d_in, const int* in_sizes, int n_in,
                              void* d_out, int out_size, void* d_ws, size_t ws_size,
                              hipStream_t stream) {
  const float* x = (const float*)d_in[0];
  const int* ei = (const int*)d_in[1];
  const int* srcv = ei;           // edge_index[0]
  const int* dstv = ei + NEDGES;  // edge_index[1]
  const float* Wl1 = (const float*)d_in[2];
  const float* bl1 = (const float*)d_in[3];
  const float* Wr1 = (const float*)d_in[4];
  const float* Wl2 = (const float*)d_in[5];
  const float* bl2 = (const float*)d_in[6];
  const float* Wr2 = (const float*)d_in[7];
  const float* Wl3 = (const float*)d_in[8];
  const float* bl3 = (const float*)d_in[9];
  const float* Wr3 = (const float*)d_in[10];
  const float* g1 = (const float*)d_in[11];
  const float* be1 = (const float*)d_in[12];
  const float* g2 = (const float*)d_in[13];
  const float* be2 = (const float*)d_in[14];

  char* ws = (char*)d_ws;
  size_t o = 0;
  int* deg = (int*)(ws + o);         o += 200192;            // 50048 ints
  int* row_start = (int*)(ws + o);   o += 200448;            // 50001 ints (+pad)
  int* cursor = (int*)(ws + o);      o += 200192;
  float* inv_deg = (float*)(ws + o); o += 200192;
  int* csr = (int*)(ws + o);         o += 3200000;           // 800000 ints
  int* blocksum = (int*)(ws + o);    o += 1024;              // 256 ints
  int* blockoff = (int*)(ws + o);    o += 1024;
  unsigned short* xb = (unsigned short*)(ws + o);  o += (size_t)50000 * 256;  // x in bf16
  unsigned short* wb1l = (unsigned short*)(ws + o); o += 32768;
  unsigned short* wb1r = (unsigned short*)(ws + o); o += 32768;
  unsigned short* wb2l = (unsigned short*)(ws + o); o += 32768;
  unsigned short* wb2r = (unsigned short*)(ws + o); o += 32768;
  unsigned short* wb3l = (unsigned short*)(ws + o); o += 16384;
  unsigned short* wb3r = (unsigned short*)(ws + o); o += 16384;
  unsigned short* aggb = (unsigned short*)(ws + o); o += (size_t)50000 * 256;
  unsigned short* h1 = (unsigned short*)(ws + o);   o += (size_t)50000 * 256;
  unsigned short* h2 = (unsigned short*)(ws + o);   o += (size_t)50000 * 256;

  dim3 blk(256);
  dim3 aggGrid(NNODES / 4);            // 4 waves/block, one node per wave
  dim3 gemmGrid((NNODES + 63) / 64);   // 64 rows per block
  dim3 scanGrid(SCAN_BLOCKS);

  // CSR build
  zero_int_kernel<<<dim3((NNODES + 255) / 256), blk, 0, stream>>>(deg, NNODES);
  degree_kernel<<<dim3(784), blk, 0, stream>>>(dstv, deg);
  block_sum_kernel<<<scanGrid, blk, 0, stream>>>(deg, blocksum);
  scan_blocksum_kernel<<<dim3(1), blk, 0, stream>>>(blocksum, blockoff);
  apply_scan_kernel<<<scanGrid, blk, 0, stream>>>(deg, blockoff, row_start, cursor, inv_deg);
  fill_part_kernel<<<dim3(FILL_NCHUNK * 8), blk, 0, stream>>>(srcv, dstv, cursor, csr);

  // fp32 -> bf16 conversions
  conv_x_kernel<<<dim3(1024), blk, 0, stream>>>(x, (ushort4*)xb, NNODES * 128 / 4);
  WPtrs wp;
  wp.src[0] = Wl1; wp.dst[0] = wb1l; wp.n[0] = 128 * 128;
  wp.src[1] = Wr1; wp.dst[1] = wb1r; wp.n[1] = 128 * 128;
  wp.src[2] = Wl2; wp.dst[2] = wb2l; wp.n[2] = 128 * 128;
  wp.src[3] = Wr2; wp.dst[3] = wb2r; wp.n[3] = 128 * 128;
  wp.src[4] = Wl3; wp.dst[4] = wb3l; wp.n[4] = 64 * 128;
  wp.src[5] = Wr3; wp.dst[5] = wb3r; wp.n[5] = 64 * 128;
  conv_weights_kernel<<<dim3((4 * 16384 + 2 * 8192 + 255) / 256), blk, 0, stream>>>(wp);

  // Layer 1
  agg_kernel<<<aggGrid, blk, 0, stream>>>(xb, aggb, row_start, csr, inv_deg);
  fused_layer_kernel<8, true, false><<<gemmGrid, blk, 0, stream>>>(
      aggb, xb, wb1l, bl1, wb1r, g1, be1, h1);
  // Layer 2
  agg_kernel<<<aggGrid, blk, 0, stream>>>(h1, aggb, row_start, csr, inv_deg);
  fused_layer_kernel<8, true, false><<<gemmGrid, blk, 0, stream>>>(
      aggb, h1, wb2l, bl2, wb2r, g2, be2, h2);
  // Layer 3 (no ReLU/LN), fp32 output
  agg_kernel<<<aggGrid, blk, 0, stream>>>(h2, aggb, row_start, csr, inv_deg);
  fused_layer_kernel<4, false, true><<<gemmGrid, blk, 0, stream>>>(
      aggb, h2, wb3l, bl3, wb3r, (const float*)nullptr, (const float*)nullptr, d_out);
}

// Round 6
// 376.146 us; speedup vs baseline: 1.0733x; 1.0733x over previous
//
#include <hip/hip_runtime.h>

#define NNODES 50000
#define NEDGES 800000
#define SCAN_BLOCKS 196  // ceil(50000/256)
#define FILL_CHUNK 7168  // 112 chunks cover 802816 >= NEDGES
#define FILL_NCHUNK 112

using bf16x8  = __attribute__((ext_vector_type(8))) __bf16;
using floatx4 = __attribute__((ext_vector_type(4))) float;

__device__ __forceinline__ float bf2f(unsigned short u) {
  unsigned int v = ((unsigned int)u) << 16;
  return __builtin_bit_cast(float, v);
}
__device__ __forceinline__ unsigned short f2bf(float f) {
  unsigned int u = __builtin_bit_cast(unsigned int, f);
  u += 0x7fffu + ((u >> 16) & 1u);  // RNE
  return (unsigned short)(u >> 16);
}

// one int4 per thread (n4 = NEDGES/4 = 200000)
__global__ __launch_bounds__(256) void degree_kernel(const int* __restrict__ dst,
                                                     int* __restrict__ deg) {
  int i = blockIdx.x * blockDim.x + threadIdx.x;
  if (i < NEDGES / 4) {
    int4 d = *((const int4*)dst + i);
    atomicAdd(&deg[d.x], 1);
    atomicAdd(&deg[d.y], 1);
    atomicAdd(&deg[d.z], 1);
    atomicAdd(&deg[d.w], 1);
  }
}

// ---- multi-block exclusive scan of deg -> row_start/cursor/inv_deg ----
__global__ __launch_bounds__(256) void block_sum_kernel(const int* __restrict__ deg,
                                                        int* __restrict__ blocksum) {
  __shared__ int s[256];
  int i = blockIdx.x * 256 + threadIdx.x;
  s[threadIdx.x] = (i < NNODES) ? deg[i] : 0;
  __syncthreads();
  for (int off = 128; off > 0; off >>= 1) {
    if (threadIdx.x < off) s[threadIdx.x] += s[threadIdx.x + off];
    __syncthreads();
  }
  if (threadIdx.x == 0) blocksum[blockIdx.x] = s[0];
}

__global__ __launch_bounds__(256) void scan_blocksum_kernel(const int* __restrict__ blocksum,
                                                            int* __restrict__ blockoff) {
  __shared__ int s[256];
  int t = threadIdx.x;
  s[t] = (t < SCAN_BLOCKS) ? blocksum[t] : 0;
  __syncthreads();
  for (int off = 1; off < 256; off <<= 1) {
    int v = s[t];
    int u = (t >= off) ? s[t - off] : 0;
    __syncthreads();
    s[t] = v + u;
    __syncthreads();
  }
  if (t < SCAN_BLOCKS) blockoff[t] = (t == 0) ? 0 : s[t - 1];
}

__global__ __launch_bounds__(256) void apply_scan_kernel(
    const int* __restrict__ deg, const int* __restrict__ blockoff,
    int* __restrict__ row_start, int* __restrict__ cursor, float* __restrict__ inv_deg) {
  __shared__ int s[256];
  int t = threadIdx.x;
  int i = blockIdx.x * 256 + t;
  int d = (i < NNODES) ? deg[i] : 0;
  s[t] = d;
  __syncthreads();
  for (int off = 1; off < 256; off <<= 1) {
    int v = s[t];
    int u = (t >= off) ? s[t - off] : 0;
    __syncthreads();
    s[t] = v + u;
    __syncthreads();
  }
  if (i < NNODES) {
    int excl = blockoff[blockIdx.x] + s[t] - d;  // inclusive - self
    row_start[i] = excl;
    cursor[i] = excl;
    inv_deg[i] = 1.0f / (float)((d > 0) ? d : 1);
  }
  if (i == 0) row_start[NNODES] = NEDGES;
}

// XCD-partitioned CSR fill (blockIdx%8 ~ XCD round-robin). 112 chunks x 8 parts
// = 896 blocks for latency hiding (round-5 lesson: this kernel is latency-bound,
// not write-BW-bound; NT loads were neutral).
__global__ __launch_bounds__(256) void fill_part_kernel(const int* __restrict__ src,
                                                        const int* __restrict__ dst,
                                                        int* __restrict__ cursor,
                                                        int* __restrict__ csr) {
  int p = blockIdx.x & 7;
  if (p == 7) return;  // dst < 50000 => partition 7 empty
  int chunk = blockIdx.x >> 3;
  int e0 = chunk * FILL_CHUNK;
  int e1 = min(e0 + FILL_CHUNK, NEDGES);
  for (int base = e0 + (int)threadIdx.x * 4; base < e1; base += 256 * 4) {
    int4 d4 = *(const int4*)(dst + base);
    int4 s4 = *(const int4*)(src + base);
    if ((d4.x >> 13) == p) { int pos = atomicAdd(&cursor[d4.x], 1); csr[pos] = s4.x; }
    if ((d4.y >> 13) == p) { int pos = atomicAdd(&cursor[d4.y], 1); csr[pos] = s4.y; }
    if ((d4.z >> 13) == p) { int pos = atomicAdd(&cursor[d4.z], 1); csr[pos] = s4.z; }
    if ((d4.w >> 13) == p) { int pos = atomicAdd(&cursor[d4.w], 1); csr[pos] = s4.w; }
  }
}

// fp32 -> bf16, vectorized: float4 in, ushort4 out
__global__ void conv_x_kernel(const float4* __restrict__ in, ushort4* __restrict__ out,
                              int n4) {
  int i = blockIdx.x * blockDim.x + threadIdx.x;
  int stride = gridDim.x * blockDim.x;
  for (; i < n4; i += stride) {
    float4 v = in[i];
    ushort4 o;
    o.x = f2bf(v.x);
    o.y = f2bf(v.y);
    o.z = f2bf(v.z);
    o.w = f2bf(v.w);
    out[i] = o;
  }
}

struct WPtrs {
  const float* src[6];
  unsigned short* dst[6];
  int n[6];
};

__global__ void conv_weights_kernel(WPtrs p) {
  int i = blockIdx.x * blockDim.x + threadIdx.x;
#pragma unroll
  for (int s = 0; s < 6; ++s) {
    if (i < p.n[s]) {
      p.dst[s][i] = f2bf(p.src[s][i]);
      return;
    }
    i -= p.n[s];
  }
}

// one wave per node; quarter-wave per edge: lane = qw*16 + c16.
// 16 lanes x uint4(16B) cover one 256B feature row; 4 edges in flight per
// load instruction; unroll 2 => 8 rows outstanding. Cross-quarter reduce via
// shfl_xor(16,32); lanes 0-15 store uint4 (coalesced 256B per wave).
__global__ __launch_bounds__(256) void agg_kernel(
    const unsigned short* __restrict__ hin, unsigned short* __restrict__ aggout,
    const int* __restrict__ row_start, const int* __restrict__ csr,
    const float* __restrict__ inv_deg) {
  int gw = (blockIdx.x * blockDim.x + threadIdx.x) >> 6;  // node id
  int lane = threadIdx.x & 63;
  int qw = lane >> 4;    // 0..3: which edge within a group of 4
  int c16 = lane & 15;   // channel group: channels [c16*8, c16*8+8)
  int off = c16 * 8;     // ushort offset within row
  int s0 = row_start[gw], s1 = row_start[gw + 1];
  float a0 = 0.f, a1 = 0.f, a2 = 0.f, a3 = 0.f, a4 = 0.f, a5 = 0.f, a6 = 0.f, a7 = 0.f;
#define ACC8(v)                                  \
  a0 += bf2f((unsigned short)((v).x & 0xffffu)); \
  a1 += bf2f((unsigned short)((v).x >> 16));     \
  a2 += bf2f((unsigned short)((v).y & 0xffffu)); \
  a3 += bf2f((unsigned short)((v).y >> 16));     \
  a4 += bf2f((unsigned short)((v).z & 0xffffu)); \
  a5 += bf2f((unsigned short)((v).z >> 16));     \
  a6 += bf2f((unsigned short)((v).w & 0xffffu)); \
  a7 += bf2f((unsigned short)((v).w >> 16));
  int e = s0 + qw;
  for (; e + 4 < s1; e += 8) {
    int i0 = csr[e], i1 = csr[e + 4];
    uint4 v0 = *(const uint4*)(hin + (size_t)i0 * 128 + off);
    uint4 v1 = *(const uint4*)(hin + (size_t)i1 * 128 + off);
    ACC8(v0) ACC8(v1)
  }
  if (e < s1) {
    int i0 = csr[e];
    uint4 v = *(const uint4*)(hin + (size_t)i0 * 128 + off);
    ACC8(v)
  }
#undef ACC8
  // reduce across the 4 quarter-waves (lanes sharing c16)
  a0 += __shfl_xor(a0, 16); a1 += __shfl_xor(a1, 16);
  a2 += __shfl_xor(a2, 16); a3 += __shfl_xor(a3, 16);
  a4 += __shfl_xor(a4, 16); a5 += __shfl_xor(a5, 16);
  a6 += __shfl_xor(a6, 16); a7 += __shfl_xor(a7, 16);
  a0 += __shfl_xor(a0, 32); a1 += __shfl_xor(a1, 32);
  a2 += __shfl_xor(a2, 32); a3 += __shfl_xor(a3, 32);
  a4 += __shfl_xor(a4, 32); a5 += __shfl_xor(a5, 32);
  a6 += __shfl_xor(a6, 32); a7 += __shfl_xor(a7, 32);
  if (qw == 0) {
    float idg = inv_deg[gw];
    uint4 o;
    o.x = (unsigned int)f2bf(a0 * idg) | ((unsigned int)f2bf(a1 * idg) << 16);
    o.y = (unsigned int)f2bf(a2 * idg) | ((unsigned int)f2bf(a3 * idg) << 16);
    o.z = (unsigned int)f2bf(a4 * idg) | ((unsigned int)f2bf(a5 * idg) << 16);
    o.w = (unsigned int)f2bf(a6 * idg) | ((unsigned int)f2bf(a7 * idg) << 16);
    *(uint4*)(aggout + (size_t)gw * 128 + off) = o;
  }
}

__device__ __forceinline__ bf16x8 load_frag(const unsigned short* p) {
  uint4 v = *(const uint4*)p;
  return __builtin_bit_cast(bf16x8, v);
}

// Fused: out[n][j] = sum_k agg[n][k]*Wl[j][k] + sum_k h[n][k]*Wr[j][k] + bl[j]
// then (optionally) ReLU + LayerNorm. One wave = 16 rows x OUTC cols, block = 4 waves.
template <int NT, bool LNRELU, bool OUTF32>
__global__ __launch_bounds__(256) void fused_layer_kernel(
    const unsigned short* __restrict__ agg, const unsigned short* __restrict__ hin,
    const unsigned short* __restrict__ Wl, const float* __restrict__ bl,
    const unsigned short* __restrict__ Wr, const float* __restrict__ g,
    const float* __restrict__ beta, void* __restrict__ hout) {
  constexpr int OUTC = NT * 16;
  int wave = threadIdx.x >> 6;
  int lane = threadIdx.x & 63;
  int quad = lane >> 4;
  int m = lane & 15;
  int row0 = blockIdx.x * 64 + wave * 16;
  int arow = min(row0 + m, NNODES - 1);  // clamp: tail rows read row 49999, stores guarded
  const unsigned short* ap = agg + (size_t)arow * 128 + quad * 8;
  const unsigned short* hp = hin + (size_t)arow * 128 + quad * 8;
  bf16x8 aA[4], aH[4];
#pragma unroll
  for (int kt = 0; kt < 4; ++kt) {
    aA[kt] = load_frag(ap + kt * 32);
    aH[kt] = load_frag(hp + kt * 32);
  }
  floatx4 acc[NT];
#pragma unroll
  for (int t = 0; t < NT; ++t) {
    int n = t * 16 + m;
    const unsigned short* wlp = Wl + n * 128 + quad * 8;
    const unsigned short* wrp = Wr + n * 128 + quad * 8;
    floatx4 c = {0.f, 0.f, 0.f, 0.f};
#pragma unroll
    for (int kt = 0; kt < 4; ++kt)
      c = __builtin_amdgcn_mfma_f32_16x16x32_bf16(aA[kt], load_frag(wlp + kt * 32), c, 0, 0, 0);
#pragma unroll
    for (int kt = 0; kt < 4; ++kt)
      c = __builtin_amdgcn_mfma_f32_16x16x32_bf16(aH[kt], load_frag(wrp + kt * 32), c, 0, 0, 0);
    acc[t] = c;
  }
  float bias[NT];
#pragma unroll
  for (int t = 0; t < NT; ++t) bias[t] = bl[t * 16 + m];

  if constexpr (LNRELU) {
    // C layout: value at (row=quad*4+r, col=t*16+m). Row stats reduce over the
    // 16 lanes sharing `quad` (contiguous lane group -> shfl_xor width 16).
    float v[NT][4];
    float s1[4] = {0.f, 0.f, 0.f, 0.f};
    float s2[4] = {0.f, 0.f, 0.f, 0.f};
#pragma unroll
    for (int t = 0; t < NT; ++t)
#pragma unroll
      for (int r = 0; r < 4; ++r) {
        float x = acc[t][r] + bias[t];
        x = x > 0.f ? x : 0.f;  // ReLU before LN
        v[t][r] = x;
        s1[r] += x;
        s2[r] += x * x;
      }
#pragma unroll
    for (int r = 0; r < 4; ++r) {
#pragma unroll
      for (int msk = 1; msk < 16; msk <<= 1) {
        s1[r] += __shfl_xor(s1[r], msk, 16);
        s2[r] += __shfl_xor(s2[r], msk, 16);
      }
    }
    float gam[NT], bet[NT];
#pragma unroll
    for (int t = 0; t < NT; ++t) {
      gam[t] = g[t * 16 + m];
      bet[t] = beta[t * 16 + m];
    }
#pragma unroll
    for (int r = 0; r < 4; ++r) {
      int grow = row0 + quad * 4 + r;
      if (grow < NNODES) {
        float mu = s1[r] * (1.0f / OUTC);
        float var = s2[r] * (1.0f / OUTC) - mu * mu;
        float rs = rsqrtf(var + 1e-5f);
#pragma unroll
        for (int t = 0; t < NT; ++t) {
          float y = (v[t][r] - mu) * rs * gam[t] + bet[t];
          ((unsigned short*)hout)[(size_t)grow * OUTC + t * 16 + m] = f2bf(y);
        }
      }
    }
  } else {
#pragma unroll
    for (int r = 0; r < 4; ++r) {
      int grow = row0 + quad * 4 + r;
      if (grow < NNODES) {
#pragma unroll
        for (int t = 0; t < NT; ++t) {
          float y = acc[t][r] + bias[t];
          if constexpr (OUTF32)
            ((float*)hout)[(size_t)grow * OUTC + t * 16 + m] = y;
          else
            ((unsigned short*)hout)[(size_t)grow * OUTC + t * 16 + m] = f2bf(y);
        }
      }
    }
  }
}

extern "C" void kernel_launch(void* const* d_in, const int* in_sizes, int n_in,
                              void* d_out, int out_size, void* d_ws, size_t ws_size,
                              hipStream_t stream) {
  const float* x = (const float*)d_in[0];
  const int* ei = (const int*)d_in[1];
  const int* srcv = ei;           // edge_index[0]
  const int* dstv = ei + NEDGES;  // edge_index[1]
  const float* Wl1 = (const float*)d_in[2];
  const float* bl1 = (const float*)d_in[3];
  const float* Wr1 = (const float*)d_in[4];
  const float* Wl2 = (const float*)d_in[5];
  const float* bl2 = (const float*)d_in[6];
  const float* Wr2 = (const float*)d_in[7];
  const float* Wl3 = (const float*)d_in[8];
  const float* bl3 = (const float*)d_in[9];
  const float* Wr3 = (const float*)d_in[10];
  const float* g1 = (const float*)d_in[11];
  const float* be1 = (const float*)d_in[12];
  const float* g2 = (const float*)d_in[13];
  const float* be2 = (const float*)d_in[14];

  char* ws = (char*)d_ws;
  size_t o = 0;
  int* deg = (int*)(ws + o);         o += 200192;            // 50048 ints
  int* row_start = (int*)(ws + o);   o += 200448;            // 50001 ints (+pad)
  int* cursor = (int*)(ws + o);      o += 200192;
  float* inv_deg = (float*)(ws + o); o += 200192;
  int* csr = (int*)(ws + o);         o += 3200000;           // 800000 ints
  int* blocksum = (int*)(ws + o);    o += 1024;              // 256 ints
  int* blockoff = (int*)(ws + o);    o += 1024;
  unsigned short* xb = (unsigned short*)(ws + o);  o += (size_t)50000 * 256;  // x in bf16
  unsigned short* wb1l = (unsigned short*)(ws + o); o += 32768;
  unsigned short* wb1r = (unsigned short*)(ws + o); o += 32768;
  unsigned short* wb2l = (unsigned short*)(ws + o); o += 32768;
  unsigned short* wb2r = (unsigned short*)(ws + o); o += 32768;
  unsigned short* wb3l = (unsigned short*)(ws + o); o += 16384;
  unsigned short* wb3r = (unsigned short*)(ws + o); o += 16384;
  unsigned short* aggb = (unsigned short*)(ws + o); o += (size_t)50000 * 256;
  unsigned short* h1 = (unsigned short*)(ws + o);   o += (size_t)50000 * 256;
  unsigned short* h2 = (unsigned short*)(ws + o);   o += (size_t)50000 * 256;

  dim3 blk(256);
  dim3 aggGrid(NNODES / 4);            // 4 waves/block, one node per wave
  dim3 gemmGrid((NNODES + 63) / 64);   // 64 rows per block
  dim3 scanGrid(SCAN_BLOCKS);

  // CSR build
  hipMemsetAsync(deg, 0, NNODES * sizeof(int), stream);
  degree_kernel<<<dim3(784), blk, 0, stream>>>(dstv, deg);
  block_sum_kernel<<<scanGrid, blk, 0, stream>>>(deg, blocksum);
  scan_blocksum_kernel<<<dim3(1), blk, 0, stream>>>(blocksum, blockoff);
  apply_scan_kernel<<<scanGrid, blk, 0, stream>>>(deg, blockoff, row_start, cursor, inv_deg);
  fill_part_kernel<<<dim3(FILL_NCHUNK * 8), blk, 0, stream>>>(srcv, dstv, cursor, csr);

  // fp32 -> bf16 conversions
  conv_x_kernel<<<dim3(1024), blk, 0, stream>>>((const float4*)x, (ushort4*)xb,
                                                NNODES * 128 / 4);
  WPtrs wp;
  wp.src[0] = Wl1; wp.dst[0] = wb1l; wp.n[0] = 128 * 128;
  wp.src[1] = Wr1; wp.dst[1] = wb1r; wp.n[1] = 128 * 128;
  wp.src[2] = Wl2; wp.dst[2] = wb2l; wp.n[2] = 128 * 128;
  wp.src[3] = Wr2; wp.dst[3] = wb2r; wp.n[3] = 128 * 128;
  wp.src[4] = Wl3; wp.dst[4] = wb3l; wp.n[4] = 64 * 128;
  wp.src[5] = Wr3; wp.dst[5] = wb3r; wp.n[5] = 64 * 128;
  conv_weights_kernel<<<dim3((4 * 16384 + 2 * 8192 + 255) / 256), blk, 0, stream>>>(wp);

  // Layer 1
  agg_kernel<<<aggGrid, blk, 0, stream>>>(xb, aggb, row_start, csr, inv_deg);
  fused_layer_kernel<8, true, false><<<gemmGrid, blk, 0, stream>>>(
      aggb, xb, wb1l, bl1, wb1r, g1, be1, h1);
  // Layer 2
  agg_kernel<<<aggGrid, blk, 0, stream>>>(h1, aggb, row_start, csr, inv_deg);
  fused_layer_kernel<8, true, false><<<gemmGrid, blk, 0, stream>>>(
      aggb, h1, wb2l, bl2, wb2r, g2, be2, h2);
  // Layer 3 (no ReLU/LN), fp32 output
  agg_kernel<<<aggGrid, blk, 0, stream>>>(h2, aggb, row_start, csr, inv_deg);
  fused_layer_kernel<4, false, true><<<gemmGrid, blk, 0, stream>>>(
      aggb, h2, wb3l, bl3, wb3r, (const float*)nullptr, (const float*)nullptr, d_out);
}

// Round 7
// 338.691 us; speedup vs baseline: 1.1920x; 1.1106x over previous
//
#include <hip/hip_runtime.h>

#define NNODES 50000
#define NEDGES 800000
#define SCAN_BLOCKS 196  // ceil(50000/256)
#define FILL_CHUNK 7168  // 112 chunks cover 802816 >= NEDGES
#define FILL_NCHUNK 112

using bf16x8  = __attribute__((ext_vector_type(8))) __bf16;
using floatx4 = __attribute__((ext_vector_type(4))) float;

__device__ __forceinline__ float bf2f(unsigned short u) {
  unsigned int v = ((unsigned int)u) << 16;
  return __builtin_bit_cast(float, v);
}
__device__ __forceinline__ unsigned short f2bf(float f) {
  unsigned int u = __builtin_bit_cast(unsigned int, f);
  u += 0x7fffu + ((u >> 16) & 1u);  // RNE
  return (unsigned short)(u >> 16);
}

// one int4 per thread (n4 = NEDGES/4 = 200000)
__global__ __launch_bounds__(256) void degree_kernel(const int* __restrict__ dst,
                                                     int* __restrict__ deg) {
  int i = blockIdx.x * blockDim.x + threadIdx.x;
  if (i < NEDGES / 4) {
    int4 d = *((const int4*)dst + i);
    atomicAdd(&deg[d.x], 1);
    atomicAdd(&deg[d.y], 1);
    atomicAdd(&deg[d.z], 1);
    atomicAdd(&deg[d.w], 1);
  }
}

__global__ __launch_bounds__(256) void block_sum_kernel(const int* __restrict__ deg,
                                                        int* __restrict__ blocksum) {
  __shared__ int s[256];
  int i = blockIdx.x * 256 + threadIdx.x;
  s[threadIdx.x] = (i < NNODES) ? deg[i] : 0;
  __syncthreads();
  for (int off = 128; off > 0; off >>= 1) {
    if (threadIdx.x < off) s[threadIdx.x] += s[threadIdx.x + off];
    __syncthreads();
  }
  if (threadIdx.x == 0) blocksum[blockIdx.x] = s[0];
}

// merged: every block scans the 196 block sums in LDS (tiny), then scans its own
// 256 degrees -> row_start/cursor/inv_deg. Saves one dispatch vs separate scan.
__global__ __launch_bounds__(256) void apply_scan_kernel(
    const int* __restrict__ deg, const int* __restrict__ blocksum,
    int* __restrict__ row_start, int* __restrict__ cursor, float* __restrict__ inv_deg) {
  __shared__ int bs[256];
  __shared__ int s[256];
  int t = threadIdx.x;
  bs[t] = (t < SCAN_BLOCKS) ? blocksum[t] : 0;
  int i = blockIdx.x * 256 + t;
  int d = (i < NNODES) ? deg[i] : 0;
  s[t] = d;
  __syncthreads();
  for (int off = 1; off < 256; off <<= 1) {
    int v1 = bs[t];
    int u1 = (t >= off) ? bs[t - off] : 0;
    int v2 = s[t];
    int u2 = (t >= off) ? s[t - off] : 0;
    __syncthreads();
    bs[t] = v1 + u1;
    s[t] = v2 + u2;
    __syncthreads();
  }
  int blockoff = (blockIdx.x == 0) ? 0 : bs[blockIdx.x - 1];
  if (i < NNODES) {
    int excl = blockoff + s[t] - d;  // inclusive - self
    row_start[i] = excl;
    cursor[i] = excl;
    inv_deg[i] = 1.0f / (float)((d > 0) ? d : 1);
  }
  if (i == 0) row_start[NNODES] = NEDGES;
}

// XCD-partitioned CSR fill (blockIdx%8 ~ XCD round-robin).
__global__ __launch_bounds__(256) void fill_part_kernel(const int* __restrict__ src,
                                                        const int* __restrict__ dst,
                                                        int* __restrict__ cursor,
                                                        int* __restrict__ csr) {
  int p = blockIdx.x & 7;
  if (p == 7) return;  // dst < 50000 => partition 7 empty
  int chunk = blockIdx.x >> 3;
  int e0 = chunk * FILL_CHUNK;
  int e1 = min(e0 + FILL_CHUNK, NEDGES);
  for (int base = e0 + (int)threadIdx.x * 4; base < e1; base += 256 * 4) {
    int4 d4 = *(const int4*)(dst + base);
    int4 s4 = *(const int4*)(src + base);
    if ((d4.x >> 13) == p) { int pos = atomicAdd(&cursor[d4.x], 1); csr[pos] = s4.x; }
    if ((d4.y >> 13) == p) { int pos = atomicAdd(&cursor[d4.y], 1); csr[pos] = s4.y; }
    if ((d4.z >> 13) == p) { int pos = atomicAdd(&cursor[d4.z], 1); csr[pos] = s4.z; }
    if ((d4.w >> 13) == p) { int pos = atomicAdd(&cursor[d4.w], 1); csr[pos] = s4.w; }
  }
}

__global__ void conv_x_kernel(const float4* __restrict__ in, ushort4* __restrict__ out,
                              int n4) {
  int i = blockIdx.x * blockDim.x + threadIdx.x;
  int stride = gridDim.x * blockDim.x;
  for (; i < n4; i += stride) {
    float4 v = in[i];
    ushort4 o;
    o.x = f2bf(v.x);
    o.y = f2bf(v.y);
    o.z = f2bf(v.z);
    o.w = f2bf(v.w);
    out[i] = o;
  }
}

struct WPtrs {
  const float* src[6];
  unsigned short* dst[6];
  int n[6];
};

__global__ void conv_weights_kernel(WPtrs p) {
  int i = blockIdx.x * blockDim.x + threadIdx.x;
#pragma unroll
  for (int s = 0; s < 6; ++s) {
    if (i < p.n[s]) {
      p.dst[s][i] = f2bf(p.src[s][i]);
      return;
    }
    i -= p.n[s];
  }
}

// one wave per node; quarter-wave per edge; 4 rows in flight per lane-group
// (16 edges per wave-iteration) for deeper memory-level parallelism.
__global__ __launch_bounds__(256) void agg_kernel(
    const unsigned short* __restrict__ hin, unsigned short* __restrict__ aggout,
    const int* __restrict__ row_start, const int* __restrict__ csr,
    const float* __restrict__ inv_deg) {
  int gw = (blockIdx.x * blockDim.x + threadIdx.x) >> 6;  // node id
  int lane = threadIdx.x & 63;
  int qw = lane >> 4;    // 0..3: edge slot within group of 4
  int c16 = lane & 15;   // channel group: channels [c16*8, c16*8+8)
  int off = c16 * 8;
  int s0 = row_start[gw], s1 = row_start[gw + 1];
  float a0 = 0.f, a1 = 0.f, a2 = 0.f, a3 = 0.f, a4 = 0.f, a5 = 0.f, a6 = 0.f, a7 = 0.f;
#define ACC8(v)                                  \
  a0 += bf2f((unsigned short)((v).x & 0xffffu)); \
  a1 += bf2f((unsigned short)((v).x >> 16));     \
  a2 += bf2f((unsigned short)((v).y & 0xffffu)); \
  a3 += bf2f((unsigned short)((v).y >> 16));     \
  a4 += bf2f((unsigned short)((v).z & 0xffffu)); \
  a5 += bf2f((unsigned short)((v).z >> 16));     \
  a6 += bf2f((unsigned short)((v).w & 0xffffu)); \
  a7 += bf2f((unsigned short)((v).w >> 16));
  int e = s0 + qw;
  for (; e + 12 < s1; e += 16) {
    int i0 = csr[e], i1 = csr[e + 4], i2 = csr[e + 8], i3 = csr[e + 12];
    uint4 v0 = *(const uint4*)(hin + (size_t)i0 * 128 + off);
    uint4 v1 = *(const uint4*)(hin + (size_t)i1 * 128 + off);
    uint4 v2 = *(const uint4*)(hin + (size_t)i2 * 128 + off);
    uint4 v3 = *(const uint4*)(hin + (size_t)i3 * 128 + off);
    ACC8(v0) ACC8(v1) ACC8(v2) ACC8(v3)
  }
  for (; e < s1; e += 4) {
    int i0 = csr[e];
    uint4 v = *(const uint4*)(hin + (size_t)i0 * 128 + off);
    ACC8(v)
  }
#undef ACC8
  a0 += __shfl_xor(a0, 16); a1 += __shfl_xor(a1, 16);
  a2 += __shfl_xor(a2, 16); a3 += __shfl_xor(a3, 16);
  a4 += __shfl_xor(a4, 16); a5 += __shfl_xor(a5, 16);
  a6 += __shfl_xor(a6, 16); a7 += __shfl_xor(a7, 16);
  a0 += __shfl_xor(a0, 32); a1 += __shfl_xor(a1, 32);
  a2 += __shfl_xor(a2, 32); a3 += __shfl_xor(a3, 32);
  a4 += __shfl_xor(a4, 32); a5 += __shfl_xor(a5, 32);
  a6 += __shfl_xor(a6, 32); a7 += __shfl_xor(a7, 32);
  if (qw == 0) {
    float idg = inv_deg[gw];
    uint4 o;
    o.x = (unsigned int)f2bf(a0 * idg) | ((unsigned int)f2bf(a1 * idg) << 16);
    o.y = (unsigned int)f2bf(a2 * idg) | ((unsigned int)f2bf(a3 * idg) << 16);
    o.z = (unsigned int)f2bf(a4 * idg) | ((unsigned int)f2bf(a5 * idg) << 16);
    o.w = (unsigned int)f2bf(a6 * idg) | ((unsigned int)f2bf(a7 * idg) << 16);
    *(uint4*)(aggout + (size_t)gw * 128 + off) = o;
  }
}

__device__ __forceinline__ bf16x8 load_frag(const unsigned short* p) {
  uint4 v = *(const uint4*)p;
  return __builtin_bit_cast(bf16x8, v);
}

// Fused GEMM+bias(+ReLU+LN). One wave = 32 rows (2 x 16-row MFMA sets sharing the
// same weight fragments -> halves per-row weight traffic, the kernel's main cost).
// Block = 4 waves = 128 rows.
template <int NT, bool LNRELU, bool OUTF32>
__global__ __launch_bounds__(256) void fused_layer_kernel(
    const unsigned short* __restrict__ agg, const unsigned short* __restrict__ hin,
    const unsigned short* __restrict__ Wl, const float* __restrict__ bl,
    const unsigned short* __restrict__ Wr, const float* __restrict__ g,
    const float* __restrict__ beta, void* __restrict__ hout) {
  constexpr int OUTC = NT * 16;
  int wave = threadIdx.x >> 6;
  int lane = threadIdx.x & 63;
  int quad = lane >> 4;
  int m = lane & 15;
  int row0 = blockIdx.x * 128 + wave * 32;
  int arow0 = min(row0 + m, NNODES - 1);       // clamped reads; stores guarded
  int arow1 = min(row0 + 16 + m, NNODES - 1);
  const unsigned short* ap0 = agg + (size_t)arow0 * 128 + quad * 8;
  const unsigned short* hp0 = hin + (size_t)arow0 * 128 + quad * 8;
  const unsigned short* ap1 = agg + (size_t)arow1 * 128 + quad * 8;
  const unsigned short* hp1 = hin + (size_t)arow1 * 128 + quad * 8;
  bf16x8 aA0[4], aH0[4], aA1[4], aH1[4];
#pragma unroll
  for (int kt = 0; kt < 4; ++kt) {
    aA0[kt] = load_frag(ap0 + kt * 32);
    aH0[kt] = load_frag(hp0 + kt * 32);
    aA1[kt] = load_frag(ap1 + kt * 32);
    aH1[kt] = load_frag(hp1 + kt * 32);
  }
  floatx4 acc[2][NT];
#pragma unroll
  for (int t = 0; t < NT; ++t) {
    int n = t * 16 + m;
    const unsigned short* wlp = Wl + n * 128 + quad * 8;
    const unsigned short* wrp = Wr + n * 128 + quad * 8;
    bf16x8 wl[4], wr[4];
#pragma unroll
    for (int kt = 0; kt < 4; ++kt) {
      wl[kt] = load_frag(wlp + kt * 32);
      wr[kt] = load_frag(wrp + kt * 32);
    }
    floatx4 c0 = {0.f, 0.f, 0.f, 0.f};
    floatx4 c1 = {0.f, 0.f, 0.f, 0.f};
#pragma unroll
    for (int kt = 0; kt < 4; ++kt) {
      c0 = __builtin_amdgcn_mfma_f32_16x16x32_bf16(aA0[kt], wl[kt], c0, 0, 0, 0);
      c1 = __builtin_amdgcn_mfma_f32_16x16x32_bf16(aA1[kt], wl[kt], c1, 0, 0, 0);
    }
#pragma unroll
    for (int kt = 0; kt < 4; ++kt) {
      c0 = __builtin_amdgcn_mfma_f32_16x16x32_bf16(aH0[kt], wr[kt], c0, 0, 0, 0);
      c1 = __builtin_amdgcn_mfma_f32_16x16x32_bf16(aH1[kt], wr[kt], c1, 0, 0, 0);
    }
    acc[0][t] = c0;
    acc[1][t] = c1;
  }
  float bias[NT];
#pragma unroll
  for (int t = 0; t < NT; ++t) bias[t] = bl[t * 16 + m];

  if constexpr (LNRELU) {
    // C layout per set: value at (row=quad*4+r, col=t*16+m); stats reduce over m.
    float s1[2][4] = {{0.f}}, s2[2][4] = {{0.f}};
#pragma unroll
    for (int sset = 0; sset < 2; ++sset)
#pragma unroll
      for (int t = 0; t < NT; ++t)
#pragma unroll
        for (int r = 0; r < 4; ++r) {
          float x = acc[sset][t][r] + bias[t];
          x = x > 0.f ? x : 0.f;
          acc[sset][t][r] = x;
          s1[sset][r] += x;
          s2[sset][r] += x * x;
        }
#pragma unroll
    for (int sset = 0; sset < 2; ++sset)
#pragma unroll
      for (int r = 0; r < 4; ++r)
#pragma unroll
        for (int msk = 1; msk < 16; msk <<= 1) {
          s1[sset][r] += __shfl_xor(s1[sset][r], msk, 16);
          s2[sset][r] += __shfl_xor(s2[sset][r], msk, 16);
        }
    float gam[NT], bet[NT];
#pragma unroll
    for (int t = 0; t < NT; ++t) {
      gam[t] = g[t * 16 + m];
      bet[t] = beta[t * 16 + m];
    }
#pragma unroll
    for (int sset = 0; sset < 2; ++sset)
#pragma unroll
      for (int r = 0; r < 4; ++r) {
        int grow = row0 + sset * 16 + quad * 4 + r;
        if (grow < NNODES) {
          float mu = s1[sset][r] * (1.0f / OUTC);
          float var = s2[sset][r] * (1.0f / OUTC) - mu * mu;
          float rs = rsqrtf(var + 1e-5f);
#pragma unroll
          for (int t = 0; t < NT; ++t) {
            float y = (acc[sset][t][r] - mu) * rs * gam[t] + bet[t];
            ((unsigned short*)hout)[(size_t)grow * OUTC + t * 16 + m] = f2bf(y);
          }
        }
      }
  } else {
#pragma unroll
    for (int sset = 0; sset < 2; ++sset)
#pragma unroll
      for (int r = 0; r < 4; ++r) {
        int grow = row0 + sset * 16 + quad * 4 + r;
        if (grow < NNODES) {
#pragma unroll
          for (int t = 0; t < NT; ++t) {
            float y = acc[sset][t][r] + bias[t];
            if constexpr (OUTF32)
              ((float*)hout)[(size_t)grow * OUTC + t * 16 + m] = y;
            else
              ((unsigned short*)hout)[(size_t)grow * OUTC + t * 16 + m] = f2bf(y);
          }
        }
      }
  }
}

extern "C" void kernel_launch(void* const* d_in, const int* in_sizes, int n_in,
                              void* d_out, int out_size, void* d_ws, size_t ws_size,
                              hipStream_t stream) {
  const float* x = (const float*)d_in[0];
  const int* ei = (const int*)d_in[1];
  const int* srcv = ei;           // edge_index[0]
  const int* dstv = ei + NEDGES;  // edge_index[1]
  const float* Wl1 = (const float*)d_in[2];
  const float* bl1 = (const float*)d_in[3];
  const float* Wr1 = (const float*)d_in[4];
  const float* Wl2 = (const float*)d_in[5];
  const float* bl2 = (const float*)d_in[6];
  const float* Wr2 = (const float*)d_in[7];
  const float* Wl3 = (const float*)d_in[8];
  const float* bl3 = (const float*)d_in[9];
  const float* Wr3 = (const float*)d_in[10];
  const float* g1 = (const float*)d_in[11];
  const float* be1 = (const float*)d_in[12];
  const float* g2 = (const float*)d_in[13];
  const float* be2 = (const float*)d_in[14];

  char* ws = (char*)d_ws;
  size_t o = 0;
  int* deg = (int*)(ws + o);         o += 200192;            // 50048 ints
  int* row_start = (int*)(ws + o);   o += 200448;            // 50001 ints (+pad)
  int* cursor = (int*)(ws + o);      o += 200192;
  float* inv_deg = (float*)(ws + o); o += 200192;
  int* csr = (int*)(ws + o);         o += 3200000;           // 800000 ints
  int* blocksum = (int*)(ws + o);    o += 1024;              // 256 ints
  unsigned short* xb = (unsigned short*)(ws + o);  o += (size_t)50000 * 256;  // x in bf16
  unsigned short* wb1l = (unsigned short*)(ws + o); o += 32768;
  unsigned short* wb1r = (unsigned short*)(ws + o); o += 32768;
  unsigned short* wb2l = (unsigned short*)(ws + o); o += 32768;
  unsigned short* wb2r = (unsigned short*)(ws + o); o += 32768;
  unsigned short* wb3l = (unsigned short*)(ws + o); o += 16384;
  unsigned short* wb3r = (unsigned short*)(ws + o); o += 16384;
  unsigned short* aggb = (unsigned short*)(ws + o); o += (size_t)50000 * 256;
  unsigned short* h1 = (unsigned short*)(ws + o);   o += (size_t)50000 * 256;
  unsigned short* h2 = (unsigned short*)(ws + o);   o += (size_t)50000 * 256;

  dim3 blk(256);
  dim3 aggGrid(NNODES / 4);             // 4 waves/block, one node per wave
  dim3 gemmGrid((NNODES + 127) / 128);  // 128 rows per block (32/wave)
  dim3 scanGrid(SCAN_BLOCKS);

  // CSR build
  hipMemsetAsync(deg, 0, NNODES * sizeof(int), stream);
  degree_kernel<<<dim3(784), blk, 0, stream>>>(dstv, deg);
  block_sum_kernel<<<scanGrid, blk, 0, stream>>>(deg, blocksum);
  apply_scan_kernel<<<scanGrid, blk, 0, stream>>>(deg, blocksum, row_start, cursor, inv_deg);
  fill_part_kernel<<<dim3(FILL_NCHUNK * 8), blk, 0, stream>>>(srcv, dstv, cursor, csr);

  // fp32 -> bf16 conversions
  conv_x_kernel<<<dim3(1024), blk, 0, stream>>>((const float4*)x, (ushort4*)xb,
                                                NNODES * 128 / 4);
  WPtrs wp;
  wp.src[0] = Wl1; wp.dst[0] = wb1l; wp.n[0] = 128 * 128;
  wp.src[1] = Wr1; wp.dst[1] = wb1r; wp.n[1] = 128 * 128;
  wp.src[2] = Wl2; wp.dst[2] = wb2l; wp.n[2] = 128 * 128;
  wp.src[3] = Wr2; wp.dst[3] = wb2r; wp.n[3] = 128 * 128;
  wp.src[4] = Wl3; wp.dst[4] = wb3l; wp.n[4] = 64 * 128;
  wp.src[5] = Wr3; wp.dst[5] = wb3r; wp.n[5] = 64 * 128;
  conv_weights_kernel<<<dim3((4 * 16384 + 2 * 8192 + 255) / 256), blk, 0, stream>>>(wp);

  // Layer 1
  agg_kernel<<<aggGrid, blk, 0, stream>>>(xb, aggb, row_start, csr, inv_deg);
  fused_layer_kernel<8, true, false><<<gemmGrid, blk, 0, stream>>>(
      aggb, xb, wb1l, bl1, wb1r, g1, be1, h1);
  // Layer 2
  agg_kernel<<<aggGrid, blk, 0, stream>>>(h1, aggb, row_start, csr, inv_deg);
  fused_layer_kernel<8, true, false><<<gemmGrid, blk, 0, stream>>>(
      aggb, h1, wb2l, bl2, wb2r, g2, be2, h2);
  // Layer 3 (no ReLU/LN), fp32 output
  agg_kernel<<<aggGrid, blk, 0, stream>>>(h2, aggb, row_start, csr, inv_deg);
  fused_layer_kernel<4, false, true><<<gemmGrid, blk, 0, stream>>>(
      aggb, h2, wb3l, bl3, wb3r, (const float*)nullptr, (const float*)nullptr, d_out);
}

// Round 8
// 333.374 us; speedup vs baseline: 1.2110x; 1.0159x over previous
//
#include <hip/hip_runtime.h>

#define NNODES 50000
#define NEDGES 800000
#define SCAN_BLOCKS 196  // ceil(50000/256)
#define FILL_CHUNK 7168  // 112 chunks cover 802816 >= NEDGES
#define FILL_NCHUNK 112

using bf16x8  = __attribute__((ext_vector_type(8))) __bf16;
using floatx4 = __attribute__((ext_vector_type(4))) float;

__device__ __forceinline__ float bf2f(unsigned short u) {
  unsigned int v = ((unsigned int)u) << 16;
  return __builtin_bit_cast(float, v);
}
__device__ __forceinline__ unsigned short f2bf(float f) {
  unsigned int u = __builtin_bit_cast(unsigned int, f);
  u += 0x7fffu + ((u >> 16) & 1u);  // RNE
  return (unsigned short)(u >> 16);
}

// one int4 per thread (n4 = NEDGES/4 = 200000)
__global__ __launch_bounds__(256) void degree_kernel(const int* __restrict__ dst,
                                                     int* __restrict__ deg) {
  int i = blockIdx.x * blockDim.x + threadIdx.x;
  if (i < NEDGES / 4) {
    int4 d = *((const int4*)dst + i);
    atomicAdd(&deg[d.x], 1);
    atomicAdd(&deg[d.y], 1);
    atomicAdd(&deg[d.z], 1);
    atomicAdd(&deg[d.w], 1);
  }
}

__global__ __launch_bounds__(256) void block_sum_kernel(const int* __restrict__ deg,
                                                        int* __restrict__ blocksum) {
  __shared__ int s[256];
  int i = blockIdx.x * 256 + threadIdx.x;
  s[threadIdx.x] = (i < NNODES) ? deg[i] : 0;
  __syncthreads();
  for (int off = 128; off > 0; off >>= 1) {
    if (threadIdx.x < off) s[threadIdx.x] += s[threadIdx.x + off];
    __syncthreads();
  }
  if (threadIdx.x == 0) blocksum[blockIdx.x] = s[0];
}

// merged: every block scans the 196 block sums in LDS, then its own 256 degrees.
__global__ __launch_bounds__(256) void apply_scan_kernel(
    const int* __restrict__ deg, const int* __restrict__ blocksum,
    int* __restrict__ row_start, int* __restrict__ cursor, float* __restrict__ inv_deg) {
  __shared__ int bs[256];
  __shared__ int s[256];
  int t = threadIdx.x;
  bs[t] = (t < SCAN_BLOCKS) ? blocksum[t] : 0;
  int i = blockIdx.x * 256 + t;
  int d = (i < NNODES) ? deg[i] : 0;
  s[t] = d;
  __syncthreads();
  for (int off = 1; off < 256; off <<= 1) {
    int v1 = bs[t];
    int u1 = (t >= off) ? bs[t - off] : 0;
    int v2 = s[t];
    int u2 = (t >= off) ? s[t - off] : 0;
    __syncthreads();
    bs[t] = v1 + u1;
    s[t] = v2 + u2;
    __syncthreads();
  }
  int blockoff = (blockIdx.x == 0) ? 0 : bs[blockIdx.x - 1];
  if (i < NNODES) {
    int excl = blockoff + s[t] - d;  // inclusive - self
    row_start[i] = excl;
    cursor[i] = excl;
    inv_deg[i] = 1.0f / (float)((d > 0) ? d : 1);
  }
  if (i == 0) row_start[NNODES] = NEDGES;
}

// XCD-partitioned CSR fill (blockIdx%8 ~ XCD round-robin heuristic).
__global__ __launch_bounds__(256) void fill_part_kernel(const int* __restrict__ src,
                                                        const int* __restrict__ dst,
                                                        int* __restrict__ cursor,
                                                        int* __restrict__ csr) {
  int p = blockIdx.x & 7;
  if (p == 7) return;  // dst < 50000 => partition 7 empty
  int chunk = blockIdx.x >> 3;
  int e0 = chunk * FILL_CHUNK;
  int e1 = min(e0 + FILL_CHUNK, NEDGES);
  for (int base = e0 + (int)threadIdx.x * 4; base < e1; base += 256 * 4) {
    int4 d4 = *(const int4*)(dst + base);
    int4 s4 = *(const int4*)(src + base);
    if ((d4.x >> 13) == p) { int pos = atomicAdd(&cursor[d4.x], 1); csr[pos] = s4.x; }
    if ((d4.y >> 13) == p) { int pos = atomicAdd(&cursor[d4.y], 1); csr[pos] = s4.y; }
    if ((d4.z >> 13) == p) { int pos = atomicAdd(&cursor[d4.z], 1); csr[pos] = s4.z; }
    if ((d4.w >> 13) == p) { int pos = atomicAdd(&cursor[d4.w], 1); csr[pos] = s4.w; }
  }
}

struct WPtrs {
  const float* src[6];
  unsigned short* dst[6];
  int n[6];
};

__global__ void conv_weights_kernel(WPtrs p) {
  int i = blockIdx.x * blockDim.x + threadIdx.x;
#pragma unroll
  for (int s = 0; s < 6; ++s) {
    if (i < p.n[s]) {
      p.dst[s][i] = f2bf(p.src[s][i]);
      return;
    }
    i -= p.n[s];
  }
}

__device__ __forceinline__ bf16x8 load_frag(const unsigned short* p) {
  uint4 v = *(const uint4*)p;
  return __builtin_bit_cast(bf16x8, v);
}
__device__ __forceinline__ bf16x8 cvt_frag(const float* p) {
  float4 v0 = *(const float4*)p;
  float4 v1 = *(const float4*)(p + 4);
  uint4 o;
  o.x = (unsigned int)f2bf(v0.x) | ((unsigned int)f2bf(v0.y) << 16);
  o.y = (unsigned int)f2bf(v0.z) | ((unsigned int)f2bf(v0.w) << 16);
  o.z = (unsigned int)f2bf(v1.x) | ((unsigned int)f2bf(v1.y) << 16);
  o.w = (unsigned int)f2bf(v1.z) | ((unsigned int)f2bf(v1.w) << 16);
  return __builtin_bit_cast(bf16x8, o);
}

// Dual GEMM: yl = A @ Wl^T, yr = A @ Wr^T (no bias/act — epilogue lives in agg).
// W = [Wl; Wr] concatenated, (NTL+NTR)*16 rows x 128. One wave = 32 rows sharing
// weight fragments; per-tile immediate store keeps VGPRs low. Block = 128 rows.
template <int NTL, int NTR, bool F32IN>
__global__ __launch_bounds__(256) void gemm_dual_kernel(
    const void* __restrict__ Ain, const unsigned short* __restrict__ W,
    unsigned short* __restrict__ yl, unsigned short* __restrict__ yr) {
  constexpr int NT = NTL + NTR;
  int wave = threadIdx.x >> 6;
  int lane = threadIdx.x & 63;
  int quad = lane >> 4;
  int m = lane & 15;
  int row0 = blockIdx.x * 128 + wave * 32;
  int ar0 = min(row0 + m, NNODES - 1);       // clamped reads; stores guarded
  int ar1 = min(row0 + 16 + m, NNODES - 1);
  bf16x8 a0[4], a1[4];
#pragma unroll
  for (int kt = 0; kt < 4; ++kt) {
    if constexpr (F32IN) {
      const float* A = (const float*)Ain;
      a0[kt] = cvt_frag(A + (size_t)ar0 * 128 + quad * 8 + kt * 32);
      a1[kt] = cvt_frag(A + (size_t)ar1 * 128 + quad * 8 + kt * 32);
    } else {
      const unsigned short* A = (const unsigned short*)Ain;
      a0[kt] = load_frag(A + (size_t)ar0 * 128 + quad * 8 + kt * 32);
      a1[kt] = load_frag(A + (size_t)ar1 * 128 + quad * 8 + kt * 32);
    }
  }
#pragma unroll
  for (int t = 0; t < NT; ++t) {
    const unsigned short* wp = W + (t * 16 + m) * 128 + quad * 8;
    bf16x8 w[4];
#pragma unroll
    for (int kt = 0; kt < 4; ++kt) w[kt] = load_frag(wp + kt * 32);
    floatx4 c0 = {0.f, 0.f, 0.f, 0.f};
    floatx4 c1 = {0.f, 0.f, 0.f, 0.f};
#pragma unroll
    for (int kt = 0; kt < 4; ++kt) {
      c0 = __builtin_amdgcn_mfma_f32_16x16x32_bf16(a0[kt], w[kt], c0, 0, 0, 0);
      c1 = __builtin_amdgcn_mfma_f32_16x16x32_bf16(a1[kt], w[kt], c1, 0, 0, 0);
    }
    // C layout: (row=quad*4+r, col=t*16+m)
#pragma unroll
    for (int r = 0; r < 4; ++r) {
      int g0 = row0 + quad * 4 + r;
      int g1r = g0 + 16;
      if (t < NTL) {
        if (g0 < NNODES) yl[(size_t)g0 * (NTL * 16) + t * 16 + m] = f2bf(c0[r]);
        if (g1r < NNODES) yl[(size_t)g1r * (NTL * 16) + t * 16 + m] = f2bf(c1[r]);
      } else {
        if (g0 < NNODES) yr[(size_t)g0 * (NTR * 16) + (t - NTL) * 16 + m] = f2bf(c0[r]);
        if (g1r < NNODES) yr[(size_t)g1r * (NTR * 16) + (t - NTL) * 16 + m] = f2bf(c1[r]);
      }
    }
  }
}

// Fused gather-mean + bias + yr + ReLU + LayerNorm -> h (bf16). One wave per node,
// quarter-wave per edge (4 rows in flight x 4-deep unroll), 128 channels.
__global__ __launch_bounds__(256) void agg_ln_kernel(
    const unsigned short* __restrict__ yl, const unsigned short* __restrict__ yr,
    const float* __restrict__ bl, const float* __restrict__ g,
    const float* __restrict__ be, const int* __restrict__ row_start,
    const int* __restrict__ csr, const float* __restrict__ inv_deg,
    unsigned short* __restrict__ hout) {
  int gw = (blockIdx.x * blockDim.x + threadIdx.x) >> 6;  // node id
  int lane = threadIdx.x & 63;
  int qw = lane >> 4;
  int c16 = lane & 15;
  int off = c16 * 8;
  int s0 = row_start[gw], s1 = row_start[gw + 1];
  float a0 = 0.f, a1 = 0.f, a2 = 0.f, a3 = 0.f, a4 = 0.f, a5 = 0.f, a6 = 0.f, a7 = 0.f;
#define ACC8(v)                                  \
  a0 += bf2f((unsigned short)((v).x & 0xffffu)); \
  a1 += bf2f((unsigned short)((v).x >> 16));     \
  a2 += bf2f((unsigned short)((v).y & 0xffffu)); \
  a3 += bf2f((unsigned short)((v).y >> 16));     \
  a4 += bf2f((unsigned short)((v).z & 0xffffu)); \
  a5 += bf2f((unsigned short)((v).z >> 16));     \
  a6 += bf2f((unsigned short)((v).w & 0xffffu)); \
  a7 += bf2f((unsigned short)((v).w >> 16));
  int e = s0 + qw;
  for (; e + 12 < s1; e += 16) {
    int i0 = csr[e], i1 = csr[e + 4], i2 = csr[e + 8], i3 = csr[e + 12];
    uint4 v0 = *(const uint4*)(yl + (size_t)i0 * 128 + off);
    uint4 v1 = *(const uint4*)(yl + (size_t)i1 * 128 + off);
    uint4 v2 = *(const uint4*)(yl + (size_t)i2 * 128 + off);
    uint4 v3 = *(const uint4*)(yl + (size_t)i3 * 128 + off);
    ACC8(v0) ACC8(v1) ACC8(v2) ACC8(v3)
  }
  for (; e < s1; e += 4) {
    int i0 = csr[e];
    uint4 v = *(const uint4*)(yl + (size_t)i0 * 128 + off);
    ACC8(v)
  }
  // sum across the 4 quarter-waves -> every lane holds the full channel sums
  a0 += __shfl_xor(a0, 16); a1 += __shfl_xor(a1, 16);
  a2 += __shfl_xor(a2, 16); a3 += __shfl_xor(a3, 16);
  a4 += __shfl_xor(a4, 16); a5 += __shfl_xor(a5, 16);
  a6 += __shfl_xor(a6, 16); a7 += __shfl_xor(a7, 16);
  a0 += __shfl_xor(a0, 32); a1 += __shfl_xor(a1, 32);
  a2 += __shfl_xor(a2, 32); a3 += __shfl_xor(a3, 32);
  a4 += __shfl_xor(a4, 32); a5 += __shfl_xor(a5, 32);
  a6 += __shfl_xor(a6, 32); a7 += __shfl_xor(a7, 32);
  float idg = inv_deg[gw];
  uint4 rv = *(const uint4*)(yr + (size_t)gw * 128 + off);
  float4 b0 = *(const float4*)(bl + off);
  float4 b1 = *(const float4*)(bl + off + 4);
  float x0 = a0 * idg + bf2f((unsigned short)(rv.x & 0xffffu)) + b0.x;
  float x1 = a1 * idg + bf2f((unsigned short)(rv.x >> 16)) + b0.y;
  float x2 = a2 * idg + bf2f((unsigned short)(rv.y & 0xffffu)) + b0.z;
  float x3 = a3 * idg + bf2f((unsigned short)(rv.y >> 16)) + b0.w;
  float x4 = a4 * idg + bf2f((unsigned short)(rv.z & 0xffffu)) + b1.x;
  float x5 = a5 * idg + bf2f((unsigned short)(rv.z >> 16)) + b1.y;
  float x6 = a6 * idg + bf2f((unsigned short)(rv.w & 0xffffu)) + b1.z;
  float x7 = a7 * idg + bf2f((unsigned short)(rv.w >> 16)) + b1.w;
  x0 = fmaxf(x0, 0.f); x1 = fmaxf(x1, 0.f); x2 = fmaxf(x2, 0.f); x3 = fmaxf(x3, 0.f);
  x4 = fmaxf(x4, 0.f); x5 = fmaxf(x5, 0.f); x6 = fmaxf(x6, 0.f); x7 = fmaxf(x7, 0.f);
  // LN stats over 128 ch: per-lane partials reduced across the 16-lane group
  float sA = x0 + x1 + x2 + x3 + x4 + x5 + x6 + x7;
  float sB = x0 * x0 + x1 * x1 + x2 * x2 + x3 * x3 + x4 * x4 + x5 * x5 + x6 * x6 + x7 * x7;
#pragma unroll
  for (int msk = 1; msk < 16; msk <<= 1) {
    sA += __shfl_xor(sA, msk, 16);
    sB += __shfl_xor(sB, msk, 16);
  }
  float mu = sA * (1.0f / 128.0f);
  float var = sB * (1.0f / 128.0f) - mu * mu;
  float rs = rsqrtf(var + 1e-5f);
  float4 g0v = *(const float4*)(g + off);
  float4 g1v = *(const float4*)(g + off + 4);
  float4 e0v = *(const float4*)(be + off);
  float4 e1v = *(const float4*)(be + off + 4);
  if (qw == 0) {
    uint4 o;
    o.x = (unsigned int)f2bf((x0 - mu) * rs * g0v.x + e0v.x) |
          ((unsigned int)f2bf((x1 - mu) * rs * g0v.y + e0v.y) << 16);
    o.y = (unsigned int)f2bf((x2 - mu) * rs * g0v.z + e0v.z) |
          ((unsigned int)f2bf((x3 - mu) * rs * g0v.w + e0v.w) << 16);
    o.z = (unsigned int)f2bf((x4 - mu) * rs * g1v.x + e1v.x) |
          ((unsigned int)f2bf((x5 - mu) * rs * g1v.y + e1v.y) << 16);
    o.w = (unsigned int)f2bf((x6 - mu) * rs * g1v.z + e1v.z) |
          ((unsigned int)f2bf((x7 - mu) * rs * g1v.w + e1v.w) << 16);
    *(uint4*)(hout + (size_t)gw * 128 + off) = o;
  }
}

// Final layer: gather-mean of 64-ch yl3 + bl3 + yr3 -> fp32 out. One wave per node,
// eighth-wave per edge (8 rows in flight x 2-deep unroll).
__global__ __launch_bounds__(256) void agg3_kernel(
    const unsigned short* __restrict__ yl, const unsigned short* __restrict__ yr,
    const float* __restrict__ bl, const int* __restrict__ row_start,
    const int* __restrict__ csr, const float* __restrict__ inv_deg,
    float* __restrict__ out) {
  int gw = (blockIdx.x * blockDim.x + threadIdx.x) >> 6;  // node id
  int lane = threadIdx.x & 63;
  int ew = lane >> 3;
  int c8 = lane & 7;
  int off = c8 * 8;
  int s0 = row_start[gw], s1 = row_start[gw + 1];
  float a0 = 0.f, a1 = 0.f, a2 = 0.f, a3 = 0.f, a4 = 0.f, a5 = 0.f, a6 = 0.f, a7 = 0.f;
  int e = s0 + ew;
  for (; e + 8 < s1; e += 16) {
    int i0 = csr[e], i1 = csr[e + 8];
    uint4 v0 = *(const uint4*)(yl + (size_t)i0 * 64 + off);
    uint4 v1 = *(const uint4*)(yl + (size_t)i1 * 64 + off);
    ACC8(v0) ACC8(v1)
  }
  for (; e < s1; e += 8) {
    int i0 = csr[e];
    uint4 v = *(const uint4*)(yl + (size_t)i0 * 64 + off);
    ACC8(v)
  }
#undef ACC8
  a0 += __shfl_xor(a0, 8);  a1 += __shfl_xor(a1, 8);
  a2 += __shfl_xor(a2, 8);  a3 += __shfl_xor(a3, 8);
  a4 += __shfl_xor(a4, 8);  a5 += __shfl_xor(a5, 8);
  a6 += __shfl_xor(a6, 8);  a7 += __shfl_xor(a7, 8);
  a0 += __shfl_xor(a0, 16); a1 += __shfl_xor(a1, 16);
  a2 += __shfl_xor(a2, 16); a3 += __shfl_xor(a3, 16);
  a4 += __shfl_xor(a4, 16); a5 += __shfl_xor(a5, 16);
  a6 += __shfl_xor(a6, 16); a7 += __shfl_xor(a7, 16);
  a0 += __shfl_xor(a0, 32); a1 += __shfl_xor(a1, 32);
  a2 += __shfl_xor(a2, 32); a3 += __shfl_xor(a3, 32);
  a4 += __shfl_xor(a4, 32); a5 += __shfl_xor(a5, 32);
  a6 += __shfl_xor(a6, 32); a7 += __shfl_xor(a7, 32);
  if (ew == 0) {
    float idg = inv_deg[gw];
    uint4 rv = *(const uint4*)(yr + (size_t)gw * 64 + off);
    float4 b0 = *(const float4*)(bl + off);
    float4 b1 = *(const float4*)(bl + off + 4);
    float4 o0, o1;
    o0.x = a0 * idg + bf2f((unsigned short)(rv.x & 0xffffu)) + b0.x;
    o0.y = a1 * idg + bf2f((unsigned short)(rv.x >> 16)) + b0.y;
    o0.z = a2 * idg + bf2f((unsigned short)(rv.y & 0xffffu)) + b0.z;
    o0.w = a3 * idg + bf2f((unsigned short)(rv.y >> 16)) + b0.w;
    o1.x = a4 * idg + bf2f((unsigned short)(rv.z & 0xffffu)) + b1.x;
    o1.y = a5 * idg + bf2f((unsigned short)(rv.z >> 16)) + b1.y;
    o1.z = a6 * idg + bf2f((unsigned short)(rv.w & 0xffffu)) + b1.z;
    o1.w = a7 * idg + bf2f((unsigned short)(rv.w >> 16)) + b1.w;
    *(float4*)(out + (size_t)gw * 64 + off) = o0;
    *(float4*)(out + (size_t)gw * 64 + off + 4) = o1;
  }
}

extern "C" void kernel_launch(void* const* d_in, const int* in_sizes, int n_in,
                              void* d_out, int out_size, void* d_ws, size_t ws_size,
                              hipStream_t stream) {
  const float* x = (const float*)d_in[0];
  const int* ei = (const int*)d_in[1];
  const int* srcv = ei;           // edge_index[0]
  const int* dstv = ei + NEDGES;  // edge_index[1]
  const float* Wl1 = (const float*)d_in[2];
  const float* bl1 = (const float*)d_in[3];
  const float* Wr1 = (const float*)d_in[4];
  const float* Wl2 = (const float*)d_in[5];
  const float* bl2 = (const float*)d_in[6];
  const float* Wr2 = (const float*)d_in[7];
  const float* Wl3 = (const float*)d_in[8];
  const float* bl3 = (const float*)d_in[9];
  const float* Wr3 = (const float*)d_in[10];
  const float* g1 = (const float*)d_in[11];
  const float* be1 = (const float*)d_in[12];
  const float* g2 = (const float*)d_in[13];
  const float* be2 = (const float*)d_in[14];

  char* ws = (char*)d_ws;
  size_t o = 0;
  int* deg = (int*)(ws + o);         o += 200192;
  int* row_start = (int*)(ws + o);   o += 200448;
  int* cursor = (int*)(ws + o);      o += 200192;
  float* inv_deg = (float*)(ws + o); o += 200192;
  int* csr = (int*)(ws + o);         o += 3200000;
  int* blocksum = (int*)(ws + o);    o += 1024;
  unsigned short* wb1 = (unsigned short*)(ws + o); o += 65536;   // [Wl1;Wr1] 256x128
  unsigned short* wb2 = (unsigned short*)(ws + o); o += 65536;   // [Wl2;Wr2]
  unsigned short* wb3 = (unsigned short*)(ws + o); o += 32768;   // [Wl3;Wr3] 128x128
  unsigned short* yl1 = (unsigned short*)(ws + o); o += (size_t)50000 * 256;
  unsigned short* yr1 = (unsigned short*)(ws + o); o += (size_t)50000 * 256;
  unsigned short* h1 = (unsigned short*)(ws + o);  o += (size_t)50000 * 256;
  unsigned short* yl2 = (unsigned short*)(ws + o); o += (size_t)50000 * 256;
  unsigned short* yr2 = (unsigned short*)(ws + o); o += (size_t)50000 * 256;
  unsigned short* h2 = (unsigned short*)(ws + o);  o += (size_t)50000 * 256;
  unsigned short* yl3 = (unsigned short*)(ws + o); o += (size_t)50000 * 128;
  unsigned short* yr3 = (unsigned short*)(ws + o); o += (size_t)50000 * 128;

  dim3 blk(256);
  dim3 aggGrid(NNODES / 4);             // 4 waves/block, one node per wave
  dim3 gemmGrid((NNODES + 127) / 128);  // 128 rows per block (32/wave)
  dim3 scanGrid(SCAN_BLOCKS);

  // CSR build
  hipMemsetAsync(deg, 0, NNODES * sizeof(int), stream);
  degree_kernel<<<dim3(784), blk, 0, stream>>>(dstv, deg);
  block_sum_kernel<<<scanGrid, blk, 0, stream>>>(deg, blocksum);
  apply_scan_kernel<<<scanGrid, blk, 0, stream>>>(deg, blocksum, row_start, cursor, inv_deg);
  fill_part_kernel<<<dim3(FILL_NCHUNK * 8), blk, 0, stream>>>(srcv, dstv, cursor, csr);

  // weights fp32 -> bf16, concatenated [Wl;Wr]
  WPtrs wp;
  wp.src[0] = Wl1; wp.dst[0] = wb1;         wp.n[0] = 128 * 128;
  wp.src[1] = Wr1; wp.dst[1] = wb1 + 16384; wp.n[1] = 128 * 128;
  wp.src[2] = Wl2; wp.dst[2] = wb2;         wp.n[2] = 128 * 128;
  wp.src[3] = Wr2; wp.dst[3] = wb2 + 16384; wp.n[3] = 128 * 128;
  wp.src[4] = Wl3; wp.dst[4] = wb3;         wp.n[4] = 64 * 128;
  wp.src[5] = Wr3; wp.dst[5] = wb3 + 8192;  wp.n[5] = 64 * 128;
  conv_weights_kernel<<<dim3(320), blk, 0, stream>>>(wp);

  // Layer 1: GEMM-first (mean commutes with the linear map), fp32 A inline-cvt
  gemm_dual_kernel<8, 8, true><<<gemmGrid, blk, 0, stream>>>(x, wb1, yl1, yr1);
  agg_ln_kernel<<<aggGrid, blk, 0, stream>>>(yl1, yr1, bl1, g1, be1, row_start, csr,
                                             inv_deg, h1);
  // Layer 2
  gemm_dual_kernel<8, 8, false><<<gemmGrid, blk, 0, stream>>>(h1, wb2, yl2, yr2);
  agg_ln_kernel<<<aggGrid, blk, 0, stream>>>(yl2, yr2, bl2, g2, be2, row_start, csr,
                                             inv_deg, h2);
  // Layer 3: 64-ch gather (half traffic), fp32 out
  gemm_dual_kernel<4, 4, false><<<gemmGrid, blk, 0, stream>>>(h2, wb3, yl3, yr3);
  agg3_kernel<<<aggGrid, blk, 0, stream>>>(yl3, yr3, bl3, row_start, csr, inv_deg,
                                           (float*)d_out);
}

// Round 9
// 320.334 us; speedup vs baseline: 1.2603x; 1.0407x over previous
//
#include <hip/hip_runtime.h>

#define NNODES 50000
#define NEDGES 800000
#define SCAN_BLOCKS 196  // ceil(50000/256)
#define FILL_CHUNK 7168  // 112 chunks cover 802816 >= NEDGES
#define FILL_NCHUNK 112
#define FILL_BLOCKS (FILL_NCHUNK * 8)
#define GEMM_BLOCKS ((NNODES + 127) / 128)

using bf16x8  = __attribute__((ext_vector_type(8))) __bf16;
using floatx4 = __attribute__((ext_vector_type(4))) float;

__device__ __forceinline__ float bf2f(unsigned short u) {
  unsigned int v = ((unsigned int)u) << 16;
  return __builtin_bit_cast(float, v);
}
__device__ __forceinline__ unsigned short f2bf(float f) {
  unsigned int u = __builtin_bit_cast(unsigned int, f);
  u += 0x7fffu + ((u >> 16) & 1u);  // RNE
  return (unsigned short)(u >> 16);
}

// one int4 per thread (n4 = NEDGES/4 = 200000)
__global__ __launch_bounds__(256) void degree_kernel(const int* __restrict__ dst,
                                                     int* __restrict__ deg) {
  int i = blockIdx.x * blockDim.x + threadIdx.x;
  if (i < NEDGES / 4) {
    int4 d = *((const int4*)dst + i);
    atomicAdd(&deg[d.x], 1);
    atomicAdd(&deg[d.y], 1);
    atomicAdd(&deg[d.z], 1);
    atomicAdd(&deg[d.w], 1);
  }
}

struct WPtrs {
  const float* src[6];
  unsigned short* dst[6];
  int n[6];
};

// merged: blocks 0..195 compute per-block degree sums; blocks 196.. convert
// the 6 weight matrices fp32->bf16 (independent work, one launch saved).
__global__ __launch_bounds__(256) void bsum_convw_kernel(const int* __restrict__ deg,
                                                         int* __restrict__ blocksum,
                                                         WPtrs p) {
  if (blockIdx.x < SCAN_BLOCKS) {
    __shared__ int s[256];
    int i = blockIdx.x * 256 + threadIdx.x;
    s[threadIdx.x] = (i < NNODES) ? deg[i] : 0;
    __syncthreads();
    for (int off = 128; off > 0; off >>= 1) {
      if (threadIdx.x < off) s[threadIdx.x] += s[threadIdx.x + off];
      __syncthreads();
    }
    if (threadIdx.x == 0) blocksum[blockIdx.x] = s[0];
  } else {
    int i = (blockIdx.x - SCAN_BLOCKS) * 256 + threadIdx.x;
#pragma unroll
    for (int s = 0; s < 6; ++s) {
      if (i < p.n[s]) {
        p.dst[s][i] = f2bf(p.src[s][i]);
        return;
      }
      i -= p.n[s];
    }
  }
}

// every block scans the 196 block sums in LDS, then its own 256 degrees.
__global__ __launch_bounds__(256) void apply_scan_kernel(
    const int* __restrict__ deg, const int* __restrict__ blocksum,
    int* __restrict__ row_start, int* __restrict__ cursor, float* __restrict__ inv_deg) {
  __shared__ int bs[256];
  __shared__ int s[256];
  int t = threadIdx.x;
  bs[t] = (t < SCAN_BLOCKS) ? blocksum[t] : 0;
  int i = blockIdx.x * 256 + t;
  int d = (i < NNODES) ? deg[i] : 0;
  s[t] = d;
  __syncthreads();
  for (int off = 1; off < 256; off <<= 1) {
    int v1 = bs[t];
    int u1 = (t >= off) ? bs[t - off] : 0;
    int v2 = s[t];
    int u2 = (t >= off) ? s[t - off] : 0;
    __syncthreads();
    bs[t] = v1 + u1;
    s[t] = v2 + u2;
    __syncthreads();
  }
  int blockoff = (blockIdx.x == 0) ? 0 : bs[blockIdx.x - 1];
  if (i < NNODES) {
    int excl = blockoff + s[t] - d;  // inclusive - self
    row_start[i] = excl;
    cursor[i] = excl;
    inv_deg[i] = 1.0f / (float)((d > 0) ? d : 1);
  }
  if (i == 0) row_start[NNODES] = NEDGES;
}

// XCD-partitioned CSR fill body (bid%8 ~ XCD round-robin heuristic).
__device__ __forceinline__ void fill_body(int bid, const int* __restrict__ src,
                                          const int* __restrict__ dst,
                                          int* __restrict__ cursor,
                                          int* __restrict__ csr) {
  int p = bid & 7;
  if (p == 7) return;  // dst < 50000 => partition 7 empty
  int chunk = bid >> 3;
  int e0 = chunk * FILL_CHUNK;
  int e1 = min(e0 + FILL_CHUNK, NEDGES);
  for (int base = e0 + (int)threadIdx.x * 4; base < e1; base += 256 * 4) {
    int4 d4 = *(const int4*)(dst + base);
    int4 s4 = *(const int4*)(src + base);
    if ((d4.x >> 13) == p) { int pos = atomicAdd(&cursor[d4.x], 1); csr[pos] = s4.x; }
    if ((d4.y >> 13) == p) { int pos = atomicAdd(&cursor[d4.y], 1); csr[pos] = s4.y; }
    if ((d4.z >> 13) == p) { int pos = atomicAdd(&cursor[d4.z], 1); csr[pos] = s4.z; }
    if ((d4.w >> 13) == p) { int pos = atomicAdd(&cursor[d4.w], 1); csr[pos] = s4.w; }
  }
}

__device__ __forceinline__ bf16x8 load_frag(const unsigned short* p) {
  uint4 v = *(const uint4*)p;
  return __builtin_bit_cast(bf16x8, v);
}
__device__ __forceinline__ bf16x8 cvt_frag(const float* p) {
  float4 v0 = *(const float4*)p;
  float4 v1 = *(const float4*)(p + 4);
  uint4 o;
  o.x = (unsigned int)f2bf(v0.x) | ((unsigned int)f2bf(v0.y) << 16);
  o.y = (unsigned int)f2bf(v0.z) | ((unsigned int)f2bf(v0.w) << 16);
  o.z = (unsigned int)f2bf(v1.x) | ((unsigned int)f2bf(v1.y) << 16);
  o.w = (unsigned int)f2bf(v1.z) | ((unsigned int)f2bf(v1.w) << 16);
  return __builtin_bit_cast(bf16x8, o);
}

// Dual GEMM body: yl = A @ Wl^T, yr = A @ Wr^T. W = [Wl;Wr], one wave = 32 rows
// sharing weight fragments; per-tile immediate store keeps VGPRs low.
template <int NTL, int NTR, bool F32IN>
__device__ __forceinline__ void gemm_dual_body(int bid, const void* __restrict__ Ain,
                                               const unsigned short* __restrict__ W,
                                               unsigned short* __restrict__ yl,
                                               unsigned short* __restrict__ yr) {
  constexpr int NT = NTL + NTR;
  int wave = threadIdx.x >> 6;
  int lane = threadIdx.x & 63;
  int quad = lane >> 4;
  int m = lane & 15;
  int row0 = bid * 128 + wave * 32;
  int ar0 = min(row0 + m, NNODES - 1);       // clamped reads; stores guarded
  int ar1 = min(row0 + 16 + m, NNODES - 1);
  bf16x8 a0[4], a1[4];
#pragma unroll
  for (int kt = 0; kt < 4; ++kt) {
    if constexpr (F32IN) {
      const float* A = (const float*)Ain;
      a0[kt] = cvt_frag(A + (size_t)ar0 * 128 + quad * 8 + kt * 32);
      a1[kt] = cvt_frag(A + (size_t)ar1 * 128 + quad * 8 + kt * 32);
    } else {
      const unsigned short* A = (const unsigned short*)Ain;
      a0[kt] = load_frag(A + (size_t)ar0 * 128 + quad * 8 + kt * 32);
      a1[kt] = load_frag(A + (size_t)ar1 * 128 + quad * 8 + kt * 32);
    }
  }
#pragma unroll
  for (int t = 0; t < NT; ++t) {
    const unsigned short* wp = W + (t * 16 + m) * 128 + quad * 8;
    bf16x8 w[4];
#pragma unroll
    for (int kt = 0; kt < 4; ++kt) w[kt] = load_frag(wp + kt * 32);
    floatx4 c0 = {0.f, 0.f, 0.f, 0.f};
    floatx4 c1 = {0.f, 0.f, 0.f, 0.f};
#pragma unroll
    for (int kt = 0; kt < 4; ++kt) {
      c0 = __builtin_amdgcn_mfma_f32_16x16x32_bf16(a0[kt], w[kt], c0, 0, 0, 0);
      c1 = __builtin_amdgcn_mfma_f32_16x16x32_bf16(a1[kt], w[kt], c1, 0, 0, 0);
    }
    // C layout: (row=quad*4+r, col=t*16+m)
#pragma unroll
    for (int r = 0; r < 4; ++r) {
      int g0 = row0 + quad * 4 + r;
      int g1r = g0 + 16;
      if (t < NTL) {
        if (g0 < NNODES) yl[(size_t)g0 * (NTL * 16) + t * 16 + m] = f2bf(c0[r]);
        if (g1r < NNODES) yl[(size_t)g1r * (NTL * 16) + t * 16 + m] = f2bf(c1[r]);
      } else {
        if (g0 < NNODES) yr[(size_t)g0 * (NTR * 16) + (t - NTL) * 16 + m] = f2bf(c0[r]);
        if (g1r < NNODES) yr[(size_t)g1r * (NTR * 16) + (t - NTL) * 16 + m] = f2bf(c1[r]);
      }
    }
  }
}

// merged: fill (latency-bound scatter, blocks 0..895) + layer-1 GEMM (MFMA-bound,
// blocks 896..1286) — independent work, overlapping pipes on co-resident CUs.
__global__ __launch_bounds__(256) void fill_gemm1_kernel(
    const int* __restrict__ src, const int* __restrict__ dst, int* __restrict__ cursor,
    int* __restrict__ csr, const float* __restrict__ x,
    const unsigned short* __restrict__ W, unsigned short* __restrict__ yl,
    unsigned short* __restrict__ yr) {
  if (blockIdx.x < FILL_BLOCKS)
    fill_body(blockIdx.x, src, dst, cursor, csr);
  else
    gemm_dual_body<8, 8, true>(blockIdx.x - FILL_BLOCKS, x, W, yl, yr);
}

template <int NTL, int NTR, bool F32IN>
__global__ __launch_bounds__(256) void gemm_dual_kernel(
    const void* __restrict__ Ain, const unsigned short* __restrict__ W,
    unsigned short* __restrict__ yl, unsigned short* __restrict__ yr) {
  gemm_dual_body<NTL, NTR, F32IN>(blockIdx.x, Ain, W, yl, yr);
}

// Fused gather-mean + bias + yr + ReLU + LayerNorm -> h (bf16). One wave per node,
// quarter-wave per edge (4 rows in flight x 4-deep main, 2-deep remainder).
__global__ __launch_bounds__(256) void agg_ln_kernel(
    const unsigned short* __restrict__ yl, const unsigned short* __restrict__ yr,
    const float* __restrict__ bl, const float* __restrict__ g,
    const float* __restrict__ be, const int* __restrict__ row_start,
    const int* __restrict__ csr, const float* __restrict__ inv_deg,
    unsigned short* __restrict__ hout) {
  int gw = (blockIdx.x * blockDim.x + threadIdx.x) >> 6;  // node id
  int lane = threadIdx.x & 63;
  int qw = lane >> 4;
  int c16 = lane & 15;
  int off = c16 * 8;
  int s0 = row_start[gw], s1 = row_start[gw + 1];
  float a0 = 0.f, a1 = 0.f, a2 = 0.f, a3 = 0.f, a4 = 0.f, a5 = 0.f, a6 = 0.f, a7 = 0.f;
#define ACC8(v)                                  \
  a0 += bf2f((unsigned short)((v).x & 0xffffu)); \
  a1 += bf2f((unsigned short)((v).x >> 16));     \
  a2 += bf2f((unsigned short)((v).y & 0xffffu)); \
  a3 += bf2f((unsigned short)((v).y >> 16));     \
  a4 += bf2f((unsigned short)((v).z & 0xffffu)); \
  a5 += bf2f((unsigned short)((v).z >> 16));     \
  a6 += bf2f((unsigned short)((v).w & 0xffffu)); \
  a7 += bf2f((unsigned short)((v).w >> 16));
  int e = s0 + qw;
  for (; e + 12 < s1; e += 16) {
    int i0 = csr[e], i1 = csr[e + 4], i2 = csr[e + 8], i3 = csr[e + 12];
    uint4 v0 = *(const uint4*)(yl + (size_t)i0 * 128 + off);
    uint4 v1 = *(const uint4*)(yl + (size_t)i1 * 128 + off);
    uint4 v2 = *(const uint4*)(yl + (size_t)i2 * 128 + off);
    uint4 v3 = *(const uint4*)(yl + (size_t)i3 * 128 + off);
    ACC8(v0) ACC8(v1) ACC8(v2) ACC8(v3)
  }
  for (; e + 4 < s1; e += 8) {  // 2-deep remainder
    int i0 = csr[e], i1 = csr[e + 4];
    uint4 v0 = *(const uint4*)(yl + (size_t)i0 * 128 + off);
    uint4 v1 = *(const uint4*)(yl + (size_t)i1 * 128 + off);
    ACC8(v0) ACC8(v1)
  }
  if (e < s1) {
    int i0 = csr[e];
    uint4 v = *(const uint4*)(yl + (size_t)i0 * 128 + off);
    ACC8(v)
  }
  // sum across the 4 quarter-waves -> every lane holds the full channel sums
  a0 += __shfl_xor(a0, 16); a1 += __shfl_xor(a1, 16);
  a2 += __shfl_xor(a2, 16); a3 += __shfl_xor(a3, 16);
  a4 += __shfl_xor(a4, 16); a5 += __shfl_xor(a5, 16);
  a6 += __shfl_xor(a6, 16); a7 += __shfl_xor(a7, 16);
  a0 += __shfl_xor(a0, 32); a1 += __shfl_xor(a1, 32);
  a2 += __shfl_xor(a2, 32); a3 += __shfl_xor(a3, 32);
  a4 += __shfl_xor(a4, 32); a5 += __shfl_xor(a5, 32);
  a6 += __shfl_xor(a6, 32); a7 += __shfl_xor(a7, 32);
  float idg = inv_deg[gw];
  uint4 rv = *(const uint4*)(yr + (size_t)gw * 128 + off);
  float4 b0 = *(const float4*)(bl + off);
  float4 b1 = *(const float4*)(bl + off + 4);
  float x0 = a0 * idg + bf2f((unsigned short)(rv.x & 0xffffu)) + b0.x;
  float x1 = a1 * idg + bf2f((unsigned short)(rv.x >> 16)) + b0.y;
  float x2 = a2 * idg + bf2f((unsigned short)(rv.y & 0xffffu)) + b0.z;
  float x3 = a3 * idg + bf2f((unsigned short)(rv.y >> 16)) + b0.w;
  float x4 = a4 * idg + bf2f((unsigned short)(rv.z & 0xffffu)) + b1.x;
  float x5 = a5 * idg + bf2f((unsigned short)(rv.z >> 16)) + b1.y;
  float x6 = a6 * idg + bf2f((unsigned short)(rv.w & 0xffffu)) + b1.z;
  float x7 = a7 * idg + bf2f((unsigned short)(rv.w >> 16)) + b1.w;
  x0 = fmaxf(x0, 0.f); x1 = fmaxf(x1, 0.f); x2 = fmaxf(x2, 0.f); x3 = fmaxf(x3, 0.f);
  x4 = fmaxf(x4, 0.f); x5 = fmaxf(x5, 0.f); x6 = fmaxf(x6, 0.f); x7 = fmaxf(x7, 0.f);
  float sA = x0 + x1 + x2 + x3 + x4 + x5 + x6 + x7;
  float sB = x0 * x0 + x1 * x1 + x2 * x2 + x3 * x3 + x4 * x4 + x5 * x5 + x6 * x6 + x7 * x7;
#pragma unroll
  for (int msk = 1; msk < 16; msk <<= 1) {
    sA += __shfl_xor(sA, msk, 16);
    sB += __shfl_xor(sB, msk, 16);
  }
  float mu = sA * (1.0f / 128.0f);
  float var = sB * (1.0f / 128.0f) - mu * mu;
  float rs = rsqrtf(var + 1e-5f);
  float4 g0v = *(const float4*)(g + off);
  float4 g1v = *(const float4*)(g + off + 4);
  float4 e0v = *(const float4*)(be + off);
  float4 e1v = *(const float4*)(be + off + 4);
  if (qw == 0) {
    uint4 o;
    o.x = (unsigned int)f2bf((x0 - mu) * rs * g0v.x + e0v.x) |
          ((unsigned int)f2bf((x1 - mu) * rs * g0v.y + e0v.y) << 16);
    o.y = (unsigned int)f2bf((x2 - mu) * rs * g0v.z + e0v.z) |
          ((unsigned int)f2bf((x3 - mu) * rs * g0v.w + e0v.w) << 16);
    o.z = (unsigned int)f2bf((x4 - mu) * rs * g1v.x + e1v.x) |
          ((unsigned int)f2bf((x5 - mu) * rs * g1v.y + e1v.y) << 16);
    o.w = (unsigned int)f2bf((x6 - mu) * rs * g1v.z + e1v.z) |
          ((unsigned int)f2bf((x7 - mu) * rs * g1v.w + e1v.w) << 16);
    *(uint4*)(hout + (size_t)gw * 128 + off) = o;
  }
}

// Final layer: gather-mean of 64-ch yl3 + bl3 + yr3 -> fp32 out. One wave per node,
// eighth-wave per edge (8 rows in flight x 2-deep unroll).
__global__ __launch_bounds__(256) void agg3_kernel(
    const unsigned short* __restrict__ yl, const unsigned short* __restrict__ yr,
    const float* __restrict__ bl, const int* __restrict__ row_start,
    const int* __restrict__ csr, const float* __restrict__ inv_deg,
    float* __restrict__ out) {
  int gw = (blockIdx.x * blockDim.x + threadIdx.x) >> 6;  // node id
  int lane = threadIdx.x & 63;
  int ew = lane >> 3;
  int c8 = lane & 7;
  int off = c8 * 8;
  int s0 = row_start[gw], s1 = row_start[gw + 1];
  float a0 = 0.f, a1 = 0.f, a2 = 0.f, a3 = 0.f, a4 = 0.f, a5 = 0.f, a6 = 0.f, a7 = 0.f;
  int e = s0 + ew;
  for (; e + 8 < s1; e += 16) {
    int i0 = csr[e], i1 = csr[e + 8];
    uint4 v0 = *(const uint4*)(yl + (size_t)i0 * 64 + off);
    uint4 v1 = *(const uint4*)(yl + (size_t)i1 * 64 + off);
    ACC8(v0) ACC8(v1)
  }
  if (e < s1) {
    int i0 = csr[e];
    uint4 v = *(const uint4*)(yl + (size_t)i0 * 64 + off);
    ACC8(v)
  }
#undef ACC8
  a0 += __shfl_xor(a0, 8);  a1 += __shfl_xor(a1, 8);
  a2 += __shfl_xor(a2, 8);  a3 += __shfl_xor(a3, 8);
  a4 += __shfl_xor(a4, 8);  a5 += __shfl_xor(a5, 8);
  a6 += __shfl_xor(a6, 8);  a7 += __shfl_xor(a7, 8);
  a0 += __shfl_xor(a0, 16); a1 += __shfl_xor(a1, 16);
  a2 += __shfl_xor(a2, 16); a3 += __shfl_xor(a3, 16);
  a4 += __shfl_xor(a4, 16); a5 += __shfl_xor(a5, 16);
  a6 += __shfl_xor(a6, 16); a7 += __shfl_xor(a7, 16);
  a0 += __shfl_xor(a0, 32); a1 += __shfl_xor(a1, 32);
  a2 += __shfl_xor(a2, 32); a3 += __shfl_xor(a3, 32);
  a4 += __shfl_xor(a4, 32); a5 += __shfl_xor(a5, 32);
  a6 += __shfl_xor(a6, 32); a7 += __shfl_xor(a7, 32);
  if (ew == 0) {
    float idg = inv_deg[gw];
    uint4 rv = *(const uint4*)(yr + (size_t)gw * 64 + off);
    float4 b0 = *(const float4*)(bl + off);
    float4 b1 = *(const float4*)(bl + off + 4);
    float4 o0, o1;
    o0.x = a0 * idg + bf2f((unsigned short)(rv.x & 0xffffu)) + b0.x;
    o0.y = a1 * idg + bf2f((unsigned short)(rv.x >> 16)) + b0.y;
    o0.z = a2 * idg + bf2f((unsigned short)(rv.y & 0xffffu)) + b0.z;
    o0.w = a3 * idg + bf2f((unsigned short)(rv.y >> 16)) + b0.w;
    o1.x = a4 * idg + bf2f((unsigned short)(rv.z & 0xffffu)) + b1.x;
    o1.y = a5 * idg + bf2f((unsigned short)(rv.z >> 16)) + b1.y;
    o1.z = a6 * idg + bf2f((unsigned short)(rv.w & 0xffffu)) + b1.z;
    o1.w = a7 * idg + bf2f((unsigned short)(rv.w >> 16)) + b1.w;
    *(float4*)(out + (size_t)gw * 64 + off) = o0;
    *(float4*)(out + (size_t)gw * 64 + off + 4) = o1;
  }
}

extern "C" void kernel_launch(void* const* d_in, const int* in_sizes, int n_in,
                              void* d_out, int out_size, void* d_ws, size_t ws_size,
                              hipStream_t stream) {
  const float* x = (const float*)d_in[0];
  const int* ei = (const int*)d_in[1];
  const int* srcv = ei;           // edge_index[0]
  const int* dstv = ei + NEDGES;  // edge_index[1]
  const float* Wl1 = (const float*)d_in[2];
  const float* bl1 = (const float*)d_in[3];
  const float* Wr1 = (const float*)d_in[4];
  const float* Wl2 = (const float*)d_in[5];
  const float* bl2 = (const float*)d_in[6];
  const float* Wr2 = (const float*)d_in[7];
  const float* Wl3 = (const float*)d_in[8];
  const float* bl3 = (const float*)d_in[9];
  const float* Wr3 = (const float*)d_in[10];
  const float* g1 = (const float*)d_in[11];
  const float* be1 = (const float*)d_in[12];
  const float* g2 = (const float*)d_in[13];
  const float* be2 = (const float*)d_in[14];

  char* ws = (char*)d_ws;
  size_t o = 0;
  int* deg = (int*)(ws + o);         o += 200192;
  int* row_start = (int*)(ws + o);   o += 200448;
  int* cursor = (int*)(ws + o);      o += 200192;
  float* inv_deg = (float*)(ws + o); o += 200192;
  int* csr = (int*)(ws + o);         o += 3200000;
  int* blocksum = (int*)(ws + o);    o += 1024;
  unsigned short* wb1 = (unsigned short*)(ws + o); o += 65536;   // [Wl1;Wr1] 256x128
  unsigned short* wb2 = (unsigned short*)(ws + o); o += 65536;   // [Wl2;Wr2]
  unsigned short* wb3 = (unsigned short*)(ws + o); o += 32768;   // [Wl3;Wr3] 128x128
  unsigned short* yl1 = (unsigned short*)(ws + o); o += (size_t)50000 * 256;
  unsigned short* yr1 = (unsigned short*)(ws + o); o += (size_t)50000 * 256;
  unsigned short* h1 = (unsigned short*)(ws + o);  o += (size_t)50000 * 256;
  unsigned short* yl2 = (unsigned short*)(ws + o); o += (size_t)50000 * 256;
  unsigned short* yr2 = (unsigned short*)(ws + o); o += (size_t)50000 * 256;
  unsigned short* h2 = (unsigned short*)(ws + o);  o += (size_t)50000 * 256;
  unsigned short* yl3 = (unsigned short*)(ws + o); o += (size_t)50000 * 128;
  unsigned short* yr3 = (unsigned short*)(ws + o); o += (size_t)50000 * 128;

  dim3 blk(256);
  dim3 aggGrid(NNODES / 4);  // 4 waves/block, one node per wave
  dim3 gemmGrid(GEMM_BLOCKS);

  WPtrs wp;
  wp.src[0] = Wl1; wp.dst[0] = wb1;         wp.n[0] = 128 * 128;
  wp.src[1] = Wr1; wp.dst[1] = wb1 + 16384; wp.n[1] = 128 * 128;
  wp.src[2] = Wl2; wp.dst[2] = wb2;         wp.n[2] = 128 * 128;
  wp.src[3] = Wr2; wp.dst[3] = wb2 + 16384; wp.n[3] = 128 * 128;
  wp.src[4] = Wl3; wp.dst[4] = wb3;         wp.n[4] = 64 * 128;
  wp.src[5] = Wr3; wp.dst[5] = wb3 + 8192;  wp.n[5] = 64 * 128;

  // CSR build + weight conversion (merged) + layer-1 GEMM overlapped with fill
  hipMemsetAsync(deg, 0, NNODES * sizeof(int), stream);
  degree_kernel<<<dim3(784), blk, 0, stream>>>(dstv, deg);
  bsum_convw_kernel<<<dim3(SCAN_BLOCKS + 320), blk, 0, stream>>>(deg, blocksum, wp);
  apply_scan_kernel<<<dim3(SCAN_BLOCKS), blk, 0, stream>>>(deg, blocksum, row_start,
                                                           cursor, inv_deg);
  fill_gemm1_kernel<<<dim3(FILL_BLOCKS + GEMM_BLOCKS), blk, 0, stream>>>(
      srcv, dstv, cursor, csr, x, wb1, yl1, yr1);

  // Layer 1 epilogue (gather-mean + bias + ReLU + LN)
  agg_ln_kernel<<<aggGrid, blk, 0, stream>>>(yl1, yr1, bl1, g1, be1, row_start, csr,
                                             inv_deg, h1);
  // Layer 2
  gemm_dual_kernel<8, 8, false><<<gemmGrid, blk, 0, stream>>>(h1, wb2, yl2, yr2);
  agg_ln_kernel<<<aggGrid, blk, 0, stream>>>(yl2, yr2, bl2, g2, be2, row_start, csr,
                                             inv_deg, h2);
  // Layer 3: 64-ch gather, fp32 out
  gemm_dual_kernel<4, 4, false><<<gemmGrid, blk, 0, stream>>>(h2, wb3, yl3, yr3);
  agg3_kernel<<<aggGrid, blk, 0, stream>>>(yl3, yr3, bl3, row_start, csr, inv_deg,
                                           (float*)d_out);
}

// Round 10
// 277.107 us; speedup vs baseline: 1.4569x; 1.1560x over previous
//
#include <hip/hip_runtime.h>

#define NNODES 50000
#define NEDGES 800000
#define FILL_CHUNK 7168  // 112 chunks cover 802816 >= NEDGES
#define FILL_NCHUNK 112
#define FILL_BLOCKS (FILL_NCHUNK * 8)
#define GEMM_BLOCKS ((NNODES + 127) / 128)
#define CAP 96  // bucket capacity per node; deg ~ Poisson(16), P(deg>=96) ~ e^-70

using bf16x8  = __attribute__((ext_vector_type(8))) __bf16;
using floatx4 = __attribute__((ext_vector_type(4))) float;

__device__ __forceinline__ float bf2f(unsigned short u) {
  unsigned int v = ((unsigned int)u) << 16;
  return __builtin_bit_cast(float, v);
}
__device__ __forceinline__ unsigned short f2bf(float f) {
  unsigned int u = __builtin_bit_cast(unsigned int, f);
  u += 0x7fffu + ((u >> 16) & 1u);  // RNE
  return (unsigned short)(u >> 16);
}

struct WPtrs {
  const float* src[6];
  unsigned short* dst[6];
  int n[6];
};

// blocks 0..319: convert the 6 weight matrices fp32->bf16;
// blocks 320..515: zero the per-node bucket counters.
__global__ __launch_bounds__(256) void convw_zero_kernel(WPtrs p, int* __restrict__ cnt) {
  if (blockIdx.x < 320) {
    int i = blockIdx.x * 256 + threadIdx.x;
#pragma unroll
    for (int s = 0; s < 6; ++s) {
      if (i < p.n[s]) {
        p.dst[s][i] = f2bf(p.src[s][i]);
        return;
      }
      i -= p.n[s];
    }
  } else {
    int i = (blockIdx.x - 320) * 256 + threadIdx.x;
    if (i < NNODES) cnt[i] = 0;
  }
}

// One-pass bucket CSR: slot = atomicAdd(cnt[dst]), bucket[dst*CAP+slot] = src.
// XCD-partitioned by dst>>13 (bid%8 ~ XCD round-robin); per-partition bucket
// region = 8192*384B = 3MB < one XCD's 4MB L2.
__device__ __forceinline__ void fill_body(int bid, const int* __restrict__ src,
                                          const int* __restrict__ dst,
                                          int* __restrict__ cnt,
                                          int* __restrict__ bucket) {
  int p = bid & 7;
  if (p == 7) return;  // dst < 50000 => partition 7 empty
  int chunk = bid >> 3;
  int e0 = chunk * FILL_CHUNK;
  int e1 = min(e0 + FILL_CHUNK, NEDGES);
  for (int base = e0 + (int)threadIdx.x * 4; base < e1; base += 256 * 4) {
    int4 d4 = *(const int4*)(dst + base);
    int4 s4 = *(const int4*)(src + base);
    if ((d4.x >> 13) == p) { int sl = atomicAdd(&cnt[d4.x], 1); bucket[(size_t)d4.x * CAP + sl] = s4.x; }
    if ((d4.y >> 13) == p) { int sl = atomicAdd(&cnt[d4.y], 1); bucket[(size_t)d4.y * CAP + sl] = s4.y; }
    if ((d4.z >> 13) == p) { int sl = atomicAdd(&cnt[d4.z], 1); bucket[(size_t)d4.z * CAP + sl] = s4.z; }
    if ((d4.w >> 13) == p) { int sl = atomicAdd(&cnt[d4.w], 1); bucket[(size_t)d4.w * CAP + sl] = s4.w; }
  }
}

__device__ __forceinline__ bf16x8 load_frag(const unsigned short* p) {
  uint4 v = *(const uint4*)p;
  return __builtin_bit_cast(bf16x8, v);
}
__device__ __forceinline__ bf16x8 cvt_frag(const float* p) {
  float4 v0 = *(const float4*)p;
  float4 v1 = *(const float4*)(p + 4);
  uint4 o;
  o.x = (unsigned int)f2bf(v0.x) | ((unsigned int)f2bf(v0.y) << 16);
  o.y = (unsigned int)f2bf(v0.z) | ((unsigned int)f2bf(v0.w) << 16);
  o.z = (unsigned int)f2bf(v1.x) | ((unsigned int)f2bf(v1.y) << 16);
  o.w = (unsigned int)f2bf(v1.z) | ((unsigned int)f2bf(v1.w) << 16);
  return __builtin_bit_cast(bf16x8, o);
}

// Dual GEMM body: yl = A @ Wl^T, yr = A @ Wr^T. W = [Wl;Wr], one wave = 32 rows
// sharing weight fragments; per-tile immediate store keeps VGPRs low.
template <int NTL, int NTR, bool F32IN>
__device__ __forceinline__ void gemm_dual_body(int bid, const void* __restrict__ Ain,
                                               const unsigned short* __restrict__ W,
                                               unsigned short* __restrict__ yl,
                                               unsigned short* __restrict__ yr) {
  constexpr int NT = NTL + NTR;
  int wave = threadIdx.x >> 6;
  int lane = threadIdx.x & 63;
  int quad = lane >> 4;
  int m = lane & 15;
  int row0 = bid * 128 + wave * 32;
  int ar0 = min(row0 + m, NNODES - 1);       // clamped reads; stores guarded
  int ar1 = min(row0 + 16 + m, NNODES - 1);
  bf16x8 a0[4], a1[4];
#pragma unroll
  for (int kt = 0; kt < 4; ++kt) {
    if constexpr (F32IN) {
      const float* A = (const float*)Ain;
      a0[kt] = cvt_frag(A + (size_t)ar0 * 128 + quad * 8 + kt * 32);
      a1[kt] = cvt_frag(A + (size_t)ar1 * 128 + quad * 8 + kt * 32);
    } else {
      const unsigned short* A = (const unsigned short*)Ain;
      a0[kt] = load_frag(A + (size_t)ar0 * 128 + quad * 8 + kt * 32);
      a1[kt] = load_frag(A + (size_t)ar1 * 128 + quad * 8 + kt * 32);
    }
  }
#pragma unroll
  for (int t = 0; t < NT; ++t) {
    const unsigned short* wp = W + (t * 16 + m) * 128 + quad * 8;
    bf16x8 w[4];
#pragma unroll
    for (int kt = 0; kt < 4; ++kt) w[kt] = load_frag(wp + kt * 32);
    floatx4 c0 = {0.f, 0.f, 0.f, 0.f};
    floatx4 c1 = {0.f, 0.f, 0.f, 0.f};
#pragma unroll
    for (int kt = 0; kt < 4; ++kt) {
      c0 = __builtin_amdgcn_mfma_f32_16x16x32_bf16(a0[kt], w[kt], c0, 0, 0, 0);
      c1 = __builtin_amdgcn_mfma_f32_16x16x32_bf16(a1[kt], w[kt], c1, 0, 0, 0);
    }
    // C layout: (row=quad*4+r, col=t*16+m)
#pragma unroll
    for (int r = 0; r < 4; ++r) {
      int g0 = row0 + quad * 4 + r;
      int g1r = g0 + 16;
      if (t < NTL) {
        if (g0 < NNODES) yl[(size_t)g0 * (NTL * 16) + t * 16 + m] = f2bf(c0[r]);
        if (g1r < NNODES) yl[(size_t)g1r * (NTL * 16) + t * 16 + m] = f2bf(c1[r]);
      } else {
        if (g0 < NNODES) yr[(size_t)g0 * (NTR * 16) + (t - NTL) * 16 + m] = f2bf(c0[r]);
        if (g1r < NNODES) yr[(size_t)g1r * (NTR * 16) + (t - NTL) * 16 + m] = f2bf(c1[r]);
      }
    }
  }
}

// merged: bucket fill (latency-bound scatter, blocks 0..895) + layer-1 GEMM
// (MFMA-bound, blocks 896..1286) — independent, overlapping pipes.
__global__ __launch_bounds__(256) void fill_gemm1_kernel(
    const int* __restrict__ src, const int* __restrict__ dst, int* __restrict__ cnt,
    int* __restrict__ bucket, const float* __restrict__ x,
    const unsigned short* __restrict__ W, unsigned short* __restrict__ yl,
    unsigned short* __restrict__ yr) {
  if (blockIdx.x < FILL_BLOCKS)
    fill_body(blockIdx.x, src, dst, cnt, bucket);
  else
    gemm_dual_body<8, 8, true>(blockIdx.x - FILL_BLOCKS, x, W, yl, yr);
}

template <int NTL, int NTR, bool F32IN>
__global__ __launch_bounds__(256) void gemm_dual_kernel(
    const void* __restrict__ Ain, const unsigned short* __restrict__ W,
    unsigned short* __restrict__ yl, unsigned short* __restrict__ yr) {
  gemm_dual_body<NTL, NTR, F32IN>(blockIdx.x, Ain, W, yl, yr);
}

// Fused gather-mean + bias + yr + ReLU + LayerNorm -> h (bf16). One wave per node,
// quarter-wave per edge (4 rows in flight x 4-deep main, 2-deep remainder).
__global__ __launch_bounds__(256) void agg_ln_kernel(
    const unsigned short* __restrict__ yl, const unsigned short* __restrict__ yr,
    const float* __restrict__ bl, const float* __restrict__ g,
    const float* __restrict__ be, const int* __restrict__ cnt,
    const int* __restrict__ bucket, unsigned short* __restrict__ hout) {
  int gw = (blockIdx.x * blockDim.x + threadIdx.x) >> 6;  // node id
  int lane = threadIdx.x & 63;
  int qw = lane >> 4;
  int c16 = lane & 15;
  int off = c16 * 8;
  int deg = cnt[gw];
  const int* bk = bucket + (size_t)gw * CAP;
  float a0 = 0.f, a1 = 0.f, a2 = 0.f, a3 = 0.f, a4 = 0.f, a5 = 0.f, a6 = 0.f, a7 = 0.f;
#define ACC8(v)                                  \
  a0 += bf2f((unsigned short)((v).x & 0xffffu)); \
  a1 += bf2f((unsigned short)((v).x >> 16));     \
  a2 += bf2f((unsigned short)((v).y & 0xffffu)); \
  a3 += bf2f((unsigned short)((v).y >> 16));     \
  a4 += bf2f((unsigned short)((v).z & 0xffffu)); \
  a5 += bf2f((unsigned short)((v).z >> 16));     \
  a6 += bf2f((unsigned short)((v).w & 0xffffu)); \
  a7 += bf2f((unsigned short)((v).w >> 16));
  int e = qw;
  for (; e + 12 < deg; e += 16) {
    int i0 = bk[e], i1 = bk[e + 4], i2 = bk[e + 8], i3 = bk[e + 12];
    uint4 v0 = *(const uint4*)(yl + (size_t)i0 * 128 + off);
    uint4 v1 = *(const uint4*)(yl + (size_t)i1 * 128 + off);
    uint4 v2 = *(const uint4*)(yl + (size_t)i2 * 128 + off);
    uint4 v3 = *(const uint4*)(yl + (size_t)i3 * 128 + off);
    ACC8(v0) ACC8(v1) ACC8(v2) ACC8(v3)
  }
  for (; e + 4 < deg; e += 8) {  // 2-deep remainder
    int i0 = bk[e], i1 = bk[e + 4];
    uint4 v0 = *(const uint4*)(yl + (size_t)i0 * 128 + off);
    uint4 v1 = *(const uint4*)(yl + (size_t)i1 * 128 + off);
    ACC8(v0) ACC8(v1)
  }
  if (e < deg) {
    int i0 = bk[e];
    uint4 v = *(const uint4*)(yl + (size_t)i0 * 128 + off);
    ACC8(v)
  }
  // sum across the 4 quarter-waves -> every lane holds the full channel sums
  a0 += __shfl_xor(a0, 16); a1 += __shfl_xor(a1, 16);
  a2 += __shfl_xor(a2, 16); a3 += __shfl_xor(a3, 16);
  a4 += __shfl_xor(a4, 16); a5 += __shfl_xor(a5, 16);
  a6 += __shfl_xor(a6, 16); a7 += __shfl_xor(a7, 16);
  a0 += __shfl_xor(a0, 32); a1 += __shfl_xor(a1, 32);
  a2 += __shfl_xor(a2, 32); a3 += __shfl_xor(a3, 32);
  a4 += __shfl_xor(a4, 32); a5 += __shfl_xor(a5, 32);
  a6 += __shfl_xor(a6, 32); a7 += __shfl_xor(a7, 32);
  float idg = 1.0f / (float)((deg > 0) ? deg : 1);
  uint4 rv = *(const uint4*)(yr + (size_t)gw * 128 + off);
  float4 b0 = *(const float4*)(bl + off);
  float4 b1 = *(const float4*)(bl + off + 4);
  float x0 = a0 * idg + bf2f((unsigned short)(rv.x & 0xffffu)) + b0.x;
  float x1 = a1 * idg + bf2f((unsigned short)(rv.x >> 16)) + b0.y;
  float x2 = a2 * idg + bf2f((unsigned short)(rv.y & 0xffffu)) + b0.z;
  float x3 = a3 * idg + bf2f((unsigned short)(rv.y >> 16)) + b0.w;
  float x4 = a4 * idg + bf2f((unsigned short)(rv.z & 0xffffu)) + b1.x;
  float x5 = a5 * idg + bf2f((unsigned short)(rv.z >> 16)) + b1.y;
  float x6 = a6 * idg + bf2f((unsigned short)(rv.w & 0xffffu)) + b1.z;
  float x7 = a7 * idg + bf2f((unsigned short)(rv.w >> 16)) + b1.w;
  x0 = fmaxf(x0, 0.f); x1 = fmaxf(x1, 0.f); x2 = fmaxf(x2, 0.f); x3 = fmaxf(x3, 0.f);
  x4 = fmaxf(x4, 0.f); x5 = fmaxf(x5, 0.f); x6 = fmaxf(x6, 0.f); x7 = fmaxf(x7, 0.f);
  float sA = x0 + x1 + x2 + x3 + x4 + x5 + x6 + x7;
  float sB = x0 * x0 + x1 * x1 + x2 * x2 + x3 * x3 + x4 * x4 + x5 * x5 + x6 * x6 + x7 * x7;
#pragma unroll
  for (int msk = 1; msk < 16; msk <<= 1) {
    sA += __shfl_xor(sA, msk, 16);
    sB += __shfl_xor(sB, msk, 16);
  }
  float mu = sA * (1.0f / 128.0f);
  float var = sB * (1.0f / 128.0f) - mu * mu;
  float rs = rsqrtf(var + 1e-5f);
  float4 g0v = *(const float4*)(g + off);
  float4 g1v = *(const float4*)(g + off + 4);
  float4 e0v = *(const float4*)(be + off);
  float4 e1v = *(const float4*)(be + off + 4);
  if (qw == 0) {
    uint4 o;
    o.x = (unsigned int)f2bf((x0 - mu) * rs * g0v.x + e0v.x) |
          ((unsigned int)f2bf((x1 - mu) * rs * g0v.y + e0v.y) << 16);
    o.y = (unsigned int)f2bf((x2 - mu) * rs * g0v.z + e0v.z) |
          ((unsigned int)f2bf((x3 - mu) * rs * g0v.w + e0v.w) << 16);
    o.z = (unsigned int)f2bf((x4 - mu) * rs * g1v.x + e1v.x) |
          ((unsigned int)f2bf((x5 - mu) * rs * g1v.y + e1v.y) << 16);
    o.w = (unsigned int)f2bf((x6 - mu) * rs * g1v.z + e1v.z) |
          ((unsigned int)f2bf((x7 - mu) * rs * g1v.w + e1v.w) << 16);
    *(uint4*)(hout + (size_t)gw * 128 + off) = o;
  }
}

// Final layer: gather-mean of 64-ch yl3 + bl3 + yr3 -> fp32 out. One wave per node,
// eighth-wave per edge (8 rows in flight x 2-deep unroll).
__global__ __launch_bounds__(256) void agg3_kernel(
    const unsigned short* __restrict__ yl, const unsigned short* __restrict__ yr,
    const float* __restrict__ bl, const int* __restrict__ cnt,
    const int* __restrict__ bucket, float* __restrict__ out) {
  int gw = (blockIdx.x * blockDim.x + threadIdx.x) >> 6;  // node id
  int lane = threadIdx.x & 63;
  int ew = lane >> 3;
  int c8 = lane & 7;
  int off = c8 * 8;
  int deg = cnt[gw];
  const int* bk = bucket + (size_t)gw * CAP;
  float a0 = 0.f, a1 = 0.f, a2 = 0.f, a3 = 0.f, a4 = 0.f, a5 = 0.f, a6 = 0.f, a7 = 0.f;
  int e = ew;
  for (; e + 8 < deg; e += 16) {
    int i0 = bk[e], i1 = bk[e + 8];
    uint4 v0 = *(const uint4*)(yl + (size_t)i0 * 64 + off);
    uint4 v1 = *(const uint4*)(yl + (size_t)i1 * 64 + off);
    ACC8(v0) ACC8(v1)
  }
  if (e < deg) {
    int i0 = bk[e];
    uint4 v = *(const uint4*)(yl + (size_t)i0 * 64 + off);
    ACC8(v)
  }
#undef ACC8
  a0 += __shfl_xor(a0, 8);  a1 += __shfl_xor(a1, 8);
  a2 += __shfl_xor(a2, 8);  a3 += __shfl_xor(a3, 8);
  a4 += __shfl_xor(a4, 8);  a5 += __shfl_xor(a5, 8);
  a6 += __shfl_xor(a6, 8);  a7 += __shfl_xor(a7, 8);
  a0 += __shfl_xor(a0, 16); a1 += __shfl_xor(a1, 16);
  a2 += __shfl_xor(a2, 16); a3 += __shfl_xor(a3, 16);
  a4 += __shfl_xor(a4, 16); a5 += __shfl_xor(a5, 16);
  a6 += __shfl_xor(a6, 16); a7 += __shfl_xor(a7, 16);
  a0 += __shfl_xor(a0, 32); a1 += __shfl_xor(a1, 32);
  a2 += __shfl_xor(a2, 32); a3 += __shfl_xor(a3, 32);
  a4 += __shfl_xor(a4, 32); a5 += __shfl_xor(a5, 32);
  a6 += __shfl_xor(a6, 32); a7 += __shfl_xor(a7, 32);
  if (ew == 0) {
    float idg = 1.0f / (float)((deg > 0) ? deg : 1);
    uint4 rv = *(const uint4*)(yr + (size_t)gw * 64 + off);
    float4 b0 = *(const float4*)(bl + off);
    float4 b1 = *(const float4*)(bl + off + 4);
    float4 o0, o1;
    o0.x = a0 * idg + bf2f((unsigned short)(rv.x & 0xffffu)) + b0.x;
    o0.y = a1 * idg + bf2f((unsigned short)(rv.x >> 16)) + b0.y;
    o0.z = a2 * idg + bf2f((unsigned short)(rv.y & 0xffffu)) + b0.z;
    o0.w = a3 * idg + bf2f((unsigned short)(rv.y >> 16)) + b0.w;
    o1.x = a4 * idg + bf2f((unsigned short)(rv.z & 0xffffu)) + b1.x;
    o1.y = a5 * idg + bf2f((unsigned short)(rv.z >> 16)) + b1.y;
    o1.z = a6 * idg + bf2f((unsigned short)(rv.w & 0xffffu)) + b1.z;
    o1.w = a7 * idg + bf2f((unsigned short)(rv.w >> 16)) + b1.w;
    *(float4*)(out + (size_t)gw * 64 + off) = o0;
    *(float4*)(out + (size_t)gw * 64 + off + 4) = o1;
  }
}

extern "C" void kernel_launch(void* const* d_in, const int* in_sizes, int n_in,
                              void* d_out, int out_size, void* d_ws, size_t ws_size,
                              hipStream_t stream) {
  const float* x = (const float*)d_in[0];
  const int* ei = (const int*)d_in[1];
  const int* srcv = ei;           // edge_index[0]
  const int* dstv = ei + NEDGES;  // edge_index[1]
  const float* Wl1 = (const float*)d_in[2];
  const float* bl1 = (const float*)d_in[3];
  const float* Wr1 = (const float*)d_in[4];
  const float* Wl2 = (const float*)d_in[5];
  const float* bl2 = (const float*)d_in[6];
  const float* Wr2 = (const float*)d_in[7];
  const float* Wl3 = (const float*)d_in[8];
  const float* bl3 = (const float*)d_in[9];
  const float* Wr3 = (const float*)d_in[10];
  const float* g1 = (const float*)d_in[11];
  const float* be1 = (const float*)d_in[12];
  const float* g2 = (const float*)d_in[13];
  const float* be2 = (const float*)d_in[14];

  char* ws = (char*)d_ws;
  size_t o = 0;
  int* cnt = (int*)(ws + o);      o += 200192;                 // 50048 ints
  int* bucket = (int*)(ws + o);   o += (size_t)NNODES * CAP * 4;  // 19.2 MB
  unsigned short* wb1 = (unsigned short*)(ws + o); o += 65536;   // [Wl1;Wr1] 256x128
  unsigned short* wb2 = (unsigned short*)(ws + o); o += 65536;   // [Wl2;Wr2]
  unsigned short* wb3 = (unsigned short*)(ws + o); o += 32768;   // [Wl3;Wr3] 128x128
  unsigned short* yl1 = (unsigned short*)(ws + o); o += (size_t)50000 * 256;
  unsigned short* yr1 = (unsigned short*)(ws + o); o += (size_t)50000 * 256;
  unsigned short* h1 = (unsigned short*)(ws + o);  o += (size_t)50000 * 256;
  unsigned short* yl2 = (unsigned short*)(ws + o); o += (size_t)50000 * 256;
  unsigned short* yr2 = (unsigned short*)(ws + o); o += (size_t)50000 * 256;
  unsigned short* h2 = (unsigned short*)(ws + o);  o += (size_t)50000 * 256;
  unsigned short* yl3 = (unsigned short*)(ws + o); o += (size_t)50000 * 128;
  unsigned short* yr3 = (unsigned short*)(ws + o); o += (size_t)50000 * 128;

  dim3 blk(256);
  dim3 aggGrid(NNODES / 4);  // 4 waves/block, one node per wave
  dim3 gemmGrid(GEMM_BLOCKS);

  WPtrs wp;
  wp.src[0] = Wl1; wp.dst[0] = wb1;         wp.n[0] = 128 * 128;
  wp.src[1] = Wr1; wp.dst[1] = wb1 + 16384; wp.n[1] = 128 * 128;
  wp.src[2] = Wl2; wp.dst[2] = wb2;         wp.n[2] = 128 * 128;
  wp.src[3] = Wr2; wp.dst[3] = wb2 + 16384; wp.n[3] = 128 * 128;
  wp.src[4] = Wl3; wp.dst[4] = wb3;         wp.n[4] = 64 * 128;
  wp.src[5] = Wr3; wp.dst[5] = wb3 + 8192;  wp.n[5] = 64 * 128;

  // weights->bf16 + cnt zeroing (one dispatch)
  convw_zero_kernel<<<dim3(320 + 196), blk, 0, stream>>>(wp, cnt);
  // one-pass bucket CSR fill overlapped with layer-1 GEMM
  fill_gemm1_kernel<<<dim3(FILL_BLOCKS + GEMM_BLOCKS), blk, 0, stream>>>(
      srcv, dstv, cnt, bucket, x, wb1, yl1, yr1);
  // Layer 1 epilogue
  agg_ln_kernel<<<aggGrid, blk, 0, stream>>>(yl1, yr1, bl1, g1, be1, cnt, bucket, h1);
  // Layer 2
  gemm_dual_kernel<8, 8, false><<<gemmGrid, blk, 0, stream>>>(h1, wb2, yl2, yr2);
  agg_ln_kernel<<<aggGrid, blk, 0, stream>>>(yl2, yr2, bl2, g2, be2, cnt, bucket, h2);
  // Layer 3: 64-ch gather, fp32 out
  gemm_dual_kernel<4, 4, false><<<gemmGrid, blk, 0, stream>>>(h2, wb3, yl3, yr3);
  agg3_kernel<<<aggGrid, blk, 0, stream>>>(yl3, yr3, bl3, cnt, bucket, (float*)d_out);
}